// Round 3
// baseline (326.367 us; speedup 1.0000x reference)
//
#include <hip/hip_runtime.h>

#define B_   4
#define N_   8192
#define D_   512
#define NH   8
#define DH   64
#define HID  512

typedef unsigned short u16;
typedef __attribute__((ext_vector_type(8))) short  bf16x8;
typedef __attribute__((ext_vector_type(8))) unsigned short u16x8;
typedef __attribute__((ext_vector_type(4))) float  f32x4;

__device__ __forceinline__ float bf2f(u16 u) {
  unsigned int i = ((unsigned int)u) << 16;
  return __builtin_bit_cast(float, i);
}
__device__ __forceinline__ u16 f2bf(float f) {
  unsigned int i = __builtin_bit_cast(unsigned int, f);
  i += 0x7fff + ((i >> 16) & 1);
  return (u16)(i >> 16);
}

#define GLOAD16(g, l) \
  __builtin_amdgcn_global_load_lds((const __attribute__((address_space(1))) void*)(g), \
                                   (__attribute__((address_space(3))) void*)(l), 16, 0, 0)

// ------------------------------------------------- tiled transpose fp32 -> bf16
__global__ __launch_bounds__(256) void transpose_f2b(const float* __restrict__ in,
                                                     u16* __restrict__ out,
                                                     int rows, int cols) {
  __shared__ u16 tile[64][65];
  int c0 = blockIdx.x * 64, r0 = blockIdx.y * 64;
  int t = threadIdx.x;
  int rl = t >> 6, cl = t & 63;
#pragma unroll
  for (int i = 0; i < 16; i++) {
    int r = i * 4 + rl;
    tile[r][cl] = f2bf(in[(long)(r0 + r) * cols + c0 + cl]);
  }
  __syncthreads();
  int c4 = t >> 6, rr = t & 63;
#pragma unroll
  for (int i = 0; i < 16; i++) {
    int c = i * 4 + c4;
    out[(long)(c0 + c) * rows + r0 + rr] = tile[rr][c];
  }
}

// ------------------------------------------------- layernorm, single HBM pass
__global__ __launch_bounds__(256) void ln_kernel(const float* __restrict__ x,
                                                 const float* __restrict__ lw,
                                                 const float* __restrict__ lb,
                                                 u16* __restrict__ h) {
  __shared__ u16 xs[32 * 520];
  __shared__ float red[2][8][32];
  __shared__ float murs[2][32];
  __shared__ float lws[512], lbs[512];
  int b = blockIdx.y, n0 = blockIdx.x * 32;
  int t = threadIdx.x;
  lws[t] = lw[t]; lws[t + 256] = lw[t + 256];
  lbs[t] = lb[t]; lbs[t + 256] = lb[t + 256];
  int tok = t & 31, dp = t >> 5;
  const float* xp = x + (long)b * D_ * N_ + n0 + tok;
  float s = 0.f, s2 = 0.f;
#pragma unroll 8
  for (int i = 0; i < 64; i++) {
    int d = dp * 64 + i;
    float v = xp[(long)d * N_];
    s += v; s2 += v * v;
    xs[tok * 520 + d] = f2bf(v);
  }
  red[0][dp][tok] = s; red[1][dp][tok] = s2;
  __syncthreads();
  if (t < 32) {
    float S1 = 0.f, S2 = 0.f;
#pragma unroll
    for (int i = 0; i < 8; i++) { S1 += red[0][i][t]; S2 += red[1][i][t]; }
    float mu = S1 * (1.0f / 512.0f);
    float var = S2 * (1.0f / 512.0f) - mu * mu;
    murs[0][t] = mu; murs[1][t] = rsqrtf(var + 1e-5f);
  }
  __syncthreads();
  int row = t >> 3, seg = t & 7;
  float mu = murs[0][row], rs = murs[1][row];
  u16* hp = h + ((long)b * N_ + n0 + row) * D_;
  const u16* xr = xs + row * 520;
#pragma unroll
  for (int c = 0; c < 8; c++) {
    int d0 = c * 64 + seg * 8;
    u16x8 in8 = *(const u16x8*)(xr + d0);
    u16x8 o;
#pragma unroll
    for (int i = 0; i < 8; i++) {
      int d = d0 + i;
      o[i] = f2bf((bf2f(in8[i]) - mu) * rs * lws[d] + lbs[d]);
    }
    *(u16x8*)(hp + d0) = o;
  }
}

// ------------------------------------------------- GEMM1: 256x256 tile, BK=64, 8 waves,
// counted-vmcnt multi-phase pipeline (T3+T4), LDS XOR-swizzle (T2), setprio (T5),
// XCD-chunked swizzle (T1). Fused exp/S/Z epilogue with 3-way stores.
__global__ __launch_bounds__(512, 2) void gemm1(const u16* __restrict__ A,
                                                const u16* __restrict__ B,
                                                u16* __restrict__ qexp,
                                                u16* __restrict__ expkT,
                                                u16* __restrict__ vT,
                                                float* __restrict__ S,
                                                float* __restrict__ Z) {
  // LDS map (u16 units): A[buf][256][64] @ 0 (buf stride 16384), B[buf][256][64] @ 32768.
  // Swizzle: 16B slot s at row r holds global slot s ^ (r&7).
  __shared__ alignas(16) u16 smem[65536];   // 128 KiB

  // XCD swizzle: nwg = 768 (6 x 128), 96 contiguous work-ids per XCD.
  int bid = blockIdx.y * 6 + blockIdx.x;
  int wid = (bid & 7) * 96 + (bid >> 3);
  int bx = wid % 6, by = wid / 6;
  int m0 = by * 256, n0 = bx * 256;

  int tid = threadIdx.x, w = tid >> 6, lane = tid & 63;
  int l15 = lane & 15, qd = lane >> 4;
  int wm = w >> 2, wn = w & 3;              // wave tile: rows [wm*128,+128), cols [wn*64,+64)

  // ---- staging geometry: one half = 128 rows x 64 cols; per wave 2 gload16 (q=0,1)
  int rl = lane >> 3;                        // 0..7
  int sg8 = ((lane & 7) ^ rl) * 8;           // inverse-swizzled global 16B-slot (u16 units)
  int ofsA[2][2], ofsB[2][2];                // [q][hs] row offsets * 512 (K)
#pragma unroll
  for (int q = 0; q < 2; q++)
#pragma unroll
    for (int hs = 0; hs < 2; hs++) {
      int r = hs * 128 + (w * 2 + q) * 8 + rl;
      ofsA[q][hs] = (m0 + r) * 512;
      ofsB[q][hs] = (n0 + r) * 512;
    }
  const u16* Ag = A + sg8;
  const u16* Bg = B + sg8;

  // ---- fragment read bases (swizzled)
  int baseA = (wm * 128 + l15) * 64 + ((qd ^ (l15 & 7)) * 8);
  int baseB = (wn * 64 + l15) * 64 + ((qd ^ (l15 & 7)) * 8);

  f32x4 zero = {0.f, 0.f, 0.f, 0.f};
  f32x4 acc[8][4];
#pragma unroll
  for (int i = 0; i < 8; i++)
#pragma unroll
    for (int j = 0; j < 4; j++) acc[i][j] = zero;

#define STG_A(buf, hs, kt) { \
    GLOAD16(Ag + ofsA[0][hs] + (kt) * 64, smem + (buf) * 16384 + (hs) * 8192 + (w * 2 + 0) * 512); \
    GLOAD16(Ag + ofsA[1][hs] + (kt) * 64, smem + (buf) * 16384 + (hs) * 8192 + (w * 2 + 1) * 512); }
#define STG_B(buf, hs, kt) { \
    GLOAD16(Bg + ofsB[0][hs] + (kt) * 64, smem + 32768 + (buf) * 16384 + (hs) * 8192 + (w * 2 + 0) * 512); \
    GLOAD16(Bg + ofsB[1][hs] + (kt) * 64, smem + 32768 + (buf) * 16384 + (hs) * 8192 + (w * 2 + 1) * 512); }

  // prologue: A(0), B(0), A(1)  (12 loads/wave); A(1) may stay in flight
  STG_A(0, 0, 0); STG_A(0, 1, 0);
  STG_B(0, 0, 0); STG_B(0, 1, 0);
  STG_A(1, 0, 1); STG_A(1, 1, 1);
  asm volatile("s_waitcnt vmcnt(4)" ::: "memory");
  __builtin_amdgcn_s_barrier();

#pragma unroll
  for (int tt = 0; tt < 8; tt++) {
    const int c = tt & 1;
    const u16* Ab = smem + c * 16384;
    const u16* Bb = smem + 32768 + c * 16384;
    bf16x8 aL[4][2], aH[4][2], bb[4][2];
    // ---- P0: read A-low + all B; MFMA m0-3 x n0-1
#pragma unroll
    for (int i = 0; i < 4; i++)
#pragma unroll
      for (int ks = 0; ks < 2; ks++)
        aL[i][ks] = *(const bf16x8*)(Ab + ((baseA + i * 1024) ^ (ks * 32)));
#pragma unroll
    for (int j = 0; j < 4; j++)
#pragma unroll
      for (int ks = 0; ks < 2; ks++)
        bb[j][ks] = *(const bf16x8*)(Bb + ((baseB + j * 1024) ^ (ks * 32)));
    __builtin_amdgcn_s_setprio(1);
#pragma unroll
    for (int i = 0; i < 4; i++)
#pragma unroll
      for (int j = 0; j < 2; j++)
#pragma unroll
        for (int ks = 0; ks < 2; ks++)
          acc[i][j] = __builtin_amdgcn_mfma_f32_16x16x32_bf16(aL[i][ks], bb[j][ks], acc[i][j], 0, 0, 0);
    __builtin_amdgcn_s_setprio(0);
    __builtin_amdgcn_s_barrier();
    // ---- P1: read A-high; stage B(tt+1) into buf c^1 (B slots dead since P0); MFMA m4-7 x n0-1
#pragma unroll
    for (int i = 0; i < 4; i++)
#pragma unroll
      for (int ks = 0; ks < 2; ks++)
        aH[i][ks] = *(const bf16x8*)(Ab + ((baseA + (4 + i) * 1024) ^ (ks * 32)));
    if (tt < 7) { STG_B(c ^ 1, 0, tt + 1); STG_B(c ^ 1, 1, tt + 1); }
    __builtin_amdgcn_s_setprio(1);
#pragma unroll
    for (int i = 0; i < 4; i++)
#pragma unroll
      for (int j = 0; j < 2; j++)
#pragma unroll
        for (int ks = 0; ks < 2; ks++)
          acc[4 + i][j] = __builtin_amdgcn_mfma_f32_16x16x32_bf16(aH[i][ks], bb[j][ks], acc[4 + i][j], 0, 0, 0);
    __builtin_amdgcn_s_setprio(0);
    __builtin_amdgcn_s_barrier();
    // ---- P2: stage A(tt+2) into buf c (A slots dead since P1); MFMA m0-7 x n2-3; counted vmcnt
    if (tt < 6) { STG_A(c, 0, tt + 2); STG_A(c, 1, tt + 2); }
    __builtin_amdgcn_s_setprio(1);
#pragma unroll
    for (int i = 0; i < 4; i++)
#pragma unroll
      for (int j = 2; j < 4; j++)
#pragma unroll
        for (int ks = 0; ks < 2; ks++)
          acc[i][j] = __builtin_amdgcn_mfma_f32_16x16x32_bf16(aL[i][ks], bb[j][ks], acc[i][j], 0, 0, 0);
#pragma unroll
    for (int i = 0; i < 4; i++)
#pragma unroll
      for (int j = 2; j < 4; j++)
#pragma unroll
        for (int ks = 0; ks < 2; ks++)
          acc[4 + i][j] = __builtin_amdgcn_mfma_f32_16x16x32_bf16(aH[i][ks], bb[j][ks], acc[4 + i][j], 0, 0, 0);
    __builtin_amdgcn_s_setprio(0);
    if (tt < 6) { asm volatile("s_waitcnt vmcnt(4)" ::: "memory"); }
    else        { asm volatile("s_waitcnt vmcnt(0)" ::: "memory"); }
    __builtin_amdgcn_s_barrier();
  }
#undef STG_A
#undef STG_B

  // ---------------- fused epilogue
  int third = n0 >> 9;
  int n0t = n0 & 511;
  int b = m0 >> 13;
  int tloc = m0 & 8191;

  if (third == 0) {
#pragma unroll
    for (int i = 0; i < 8; i++)
#pragma unroll
      for (int j = 0; j < 4; j++)
#pragma unroll
        for (int r = 0; r < 4; r++) acc[i][j][r] = __expf(acc[i][j][r] * 0.125f);
    // column sums -> S (softmax over tokens denominators)
#pragma unroll
    for (int j = 0; j < 4; j++) {
      float ps = 0.f;
#pragma unroll
      for (int i = 0; i < 8; i++)
#pragma unroll
        for (int r = 0; r < 4; r++) ps += acc[i][j][r];
      ps += __shfl_xor(ps, 16);
      ps += __shfl_xor(ps, 32);
      if (qd == 0) atomicAdd(S + b * 512 + n0t + wn * 64 + j * 16 + l15, ps);
    }
  } else if (third == 1) {
#pragma unroll
    for (int i = 0; i < 8; i++)
#pragma unroll
      for (int j = 0; j < 4; j++)
#pragma unroll
        for (int r = 0; r < 4; r++) acc[i][j][r] = __expf(acc[i][j][r]);
    int head = (n0t >> 6) + wn;
#pragma unroll
    for (int i = 0; i < 8; i++)
#pragma unroll
      for (int r = 0; r < 4; r++) {
        float rs = acc[i][0][r] + acc[i][1][r] + acc[i][2][r] + acc[i][3][r];
        rs += __shfl_xor(rs, 1);
        rs += __shfl_xor(rs, 2);
        rs += __shfl_xor(rs, 4);
        rs += __shfl_xor(rs, 8);
        if (l15 == 0)
          atomicAdd(Z + ((long)b * NH + head) * 8192 + tloc + wm * 128 + i * 16 + qd * 4 + r, rs);
      }
  }

  // stores via LDS restage (aliases staging buffers), two 128-row halves
  u16* Cs = smem;
  if (third == 0) {
    u16* dstb = qexp + ((long)b * 8192 + tloc) * 512 + n0t;
#pragma unroll
    for (int hh = 0; hh < 2; hh++) {
      if (hh) __syncthreads();
      if (wm == hh) {
#pragma unroll
        for (int i = 0; i < 8; i++)
#pragma unroll
          for (int r = 0; r < 4; r++)
#pragma unroll
            for (int j = 0; j < 4; j++)
              Cs[(i * 16 + qd * 4 + r) * 264 + wn * 64 + j * 16 + l15] = f2bf(acc[i][j][r]);
      }
      __syncthreads();
      u16* dst = dstb + (long)hh * 128 * 512;
#pragma unroll
      for (int z = 0; z < 8; z++) {
        int row = z * 16 + (tid >> 5);
        int off = (tid & 31) * 8;
        *(uint4*)(dst + (long)row * 512 + off) = *(const uint4*)(Cs + row * 264 + off);
      }
    }
  } else {
    u16* dstb = (third == 1 ? expkT : vT) + ((long)b * 512 + n0t) * 8192 + tloc;
#pragma unroll
    for (int hh = 0; hh < 2; hh++) {
      if (hh) __syncthreads();
      if (wm == hh) {
#pragma unroll
        for (int i = 0; i < 8; i++)
#pragma unroll
          for (int r = 0; r < 4; r++)
#pragma unroll
            for (int j = 0; j < 4; j++)
              Cs[(wn * 64 + j * 16 + l15) * 136 + i * 16 + qd * 4 + r] = f2bf(acc[i][j][r]);
      }
      __syncthreads();
#pragma unroll
      for (int z = 0; z < 8; z++) {
        int col = z * 32 + (tid >> 4);
        int moff = (tid & 15) * 8;
        *(uint4*)(dstb + (long)col * 8192 + hh * 128 + moff) = *(const uint4*)(Cs + col * 136 + moff);
      }
    }
  }
}

// ------------------------------------------------- Z -> 1/Z
__global__ __launch_bounds__(256) void zrecip(float* __restrict__ Z) {
  int i = blockIdx.x * 256 + threadIdx.x;
  Z[i] = 1.0f / Z[i];
}

// ------------------------------------------------- ctx[b,h,d,e] += sum_n expkT[d,n] * vT[e,n] * Zr[b,h,n]
__global__ __launch_bounds__(256) void ctx_kernel(const u16* __restrict__ expkT,
                                                  const u16* __restrict__ vT,
                                                  const float* __restrict__ Zr,
                                                  float* __restrict__ ctx) {
  __shared__ u16 As[64 * 128];
  __shared__ u16 Bs[64 * 128];
  int kc = blockIdx.x, hh = blockIdx.y, b = blockIdx.z;
  int t = threadIdx.x, w = t >> 6, l = t & 63, l15 = l & 15, qd = l >> 4;
  long nbase = (long)kc * 512;
  const u16* Abase = expkT + ((long)b * 512 + hh * 64) * 8192 + nbase;
  const u16* Bbase = vT   + ((long)b * 512 + hh * 64) * 8192 + nbase;
  const float* Zb = Zr + ((long)b * NH + hh) * 8192 + nbase;

  f32x4 zero = {0.f, 0.f, 0.f, 0.f};
  f32x4 acc[4] = {zero, zero, zero, zero};

  int brow = t >> 2;
  for (int s = 0; s < 4; s++) {
    long ko = (long)s * 128;
    __syncthreads();
#pragma unroll
    for (int si = 0; si < 4; si++) {
      int qq = si * 4 + w;
      int row = qq * 4 + (l >> 4);
      int gs = (l & 15) ^ (row & 15);
      GLOAD16(Abase + (long)row * 8192 + ko + gs * 8, As + qq * 512);
    }
    {
      const u16* src = Bbase + (long)brow * 8192 + ko;
#pragma unroll
      for (int cc = 0; cc < 4; cc++) {
        int c = (t & 3) * 4 + cc;
        u16x8 v8 = *(const u16x8*)(src + c * 8);
        float4 z0 = *(const float4*)(Zb + ko + c * 8);
        float4 z1 = *(const float4*)(Zb + ko + c * 8 + 4);
        u16x8 o;
        o[0] = f2bf(bf2f(v8[0]) * z0.x); o[1] = f2bf(bf2f(v8[1]) * z0.y);
        o[2] = f2bf(bf2f(v8[2]) * z0.z); o[3] = f2bf(bf2f(v8[3]) * z0.w);
        o[4] = f2bf(bf2f(v8[4]) * z1.x); o[5] = f2bf(bf2f(v8[5]) * z1.y);
        o[6] = f2bf(bf2f(v8[6]) * z1.z); o[7] = f2bf(bf2f(v8[7]) * z1.w);
        *(u16x8*)(Bs + brow * 128 + ((c ^ (brow & 15)) * 8)) = o;
      }
    }
    __syncthreads();
#pragma unroll
    for (int kk = 0; kk < 4; kk++) {
      int ar = w * 16 + l15;
      bf16x8 af = *(const bf16x8*)(As + ar * 128 + (((kk * 4 + qd) ^ (ar & 15)) * 8));
#pragma unroll
      for (int j = 0; j < 4; j++) {
        int br = j * 16 + l15;
        bf16x8 bf8 = *(const bf16x8*)(Bs + br * 128 + (((kk * 4 + qd) ^ (br & 15)) * 8));
        acc[j] = __builtin_amdgcn_mfma_f32_16x16x32_bf16(af, bf8, acc[j], 0, 0, 0);
      }
    }
  }
  float* cp = ctx + ((long)(b * NH + hh)) * DH * DH;
#pragma unroll
  for (int j = 0; j < 4; j++)
#pragma unroll
    for (int r = 0; r < 4; r++)
      atomicAdd(cp + (w * 16 + qd * 4 + r) * 64 + j * 16 + l15, acc[j][r]);
}

// ------------------------------------------------- mprime
__global__ __launch_bounds__(256) void mprime(const float* __restrict__ ctx,
                                              const float* __restrict__ wout,
                                              const float* __restrict__ S,
                                              u16* __restrict__ Mt) {
  __shared__ float ws[64 * 65];
  __shared__ float cs[64 * 65];
  int dt = blockIdx.x, hh = blockIdx.y, b = blockIdx.z;
  int t = threadIdx.x;
  {
    int e = t >> 2;
#pragma unroll
    for (int ii = 0; ii < 4; ii++) {
      int col = (t & 3) * 16 + ii * 4;
      float4 v = *(const float4*)(wout + (long)(hh * 64 + e) * 512 + dt * 64 + col);
      ws[e * 65 + col] = v.x; ws[e * 65 + col + 1] = v.y;
      ws[e * 65 + col + 2] = v.z; ws[e * 65 + col + 3] = v.w;
      float4 c = *(const float4*)(ctx + ((long)(b * NH + hh)) * 4096 + (long)e * 64 + col);
      cs[e * 65 + col] = c.x; cs[e * 65 + col + 1] = c.y;
      cs[e * 65 + col + 2] = c.z; cs[e * 65 + col + 3] = c.w;
    }
  }
  __syncthreads();
  int dol = t & 63, dg = t >> 6;
#pragma unroll
  for (int dd = 0; dd < 16; dd++) {
    int d = dg * 16 + dd;
    float v = 0.f;
#pragma unroll 8
    for (int e = 0; e < 64; e++) v += cs[d * 65 + e] * ws[e * 65 + dol];
    float sv = S[b * 512 + hh * 64 + d];
    Mt[(long)b * 262144 + (long)(dt * 64 + dol) * 512 + hh * 64 + d] = f2bf(v / sv);
  }
}

// ------------------------------------------------- GEMM2 (TN), fp32 out + bias
__global__ __launch_bounds__(256) void gemm_tn_f(const u16* __restrict__ A,
                                                 const u16* __restrict__ B,
                                                 float* __restrict__ C,
                                                 const float* __restrict__ bias,
                                                 int K, int ldc,
                                                 long sA, long sB, long sC) {
  __shared__ alignas(16) u16 smem[17408];
  float* Cf = (float*)smem;

  int bid = (blockIdx.z * gridDim.y + blockIdx.y) * gridDim.x + blockIdx.x;
  int wid = (bid & 7) * 128 + (bid >> 3);
  int mx = wid & 3;
  int ny = (wid >> 2) & 63;
  long bz = wid >> 8;
  A += bz * sA; B += bz * sB; C += bz * sC;
  int m0 = mx * 128, n0 = ny * 128;

  int tid = threadIdx.x, wave = tid >> 6, lane = tid & 63;
  int l15 = lane & 15, qd = lane >> 4;

  int ra0 = tid >> 2,          qa0 = (tid & 3) ^ ((ra0 >> 1) & 3);
  int ra1 = (tid + 256) >> 2,  qa1 = (tid & 3) ^ ((ra1 >> 1) & 3);
  const u16* gA0 = A + (long)(m0 + ra0) * K + qa0 * 8;
  const u16* gA1 = A + (long)(m0 + ra1) * K + qa1 * 8;
  const u16* gB0 = B + (long)(n0 + ra0) * K + qa0 * 8;
  const u16* gB1 = B + (long)(n0 + ra1) * K + qa1 * 8;

  int wm = wave & 1, wn = wave >> 1;
  int aoff[4], boff[4];
#pragma unroll
  for (int i = 0; i < 4; i++) {
    int r = wm * 64 + i * 16 + l15;
    aoff[i] = r * 32 + ((qd ^ ((r >> 1) & 3)) * 8);
    int rb = wn * 64 + i * 16 + l15;
    boff[i] = rb * 32 + ((qd ^ ((rb >> 1) & 3)) * 8);
  }

  f32x4 zero = {0.f, 0.f, 0.f, 0.f};
  f32x4 acc[4][4];
#pragma unroll
  for (int i = 0; i < 4; i++)
#pragma unroll
    for (int j = 0; j < 4; j++) acc[i][j] = zero;

#define STAGE2(buf, kk) { \
    u16* dA = smem + (buf) * 8192 + wave * 512; \
    u16* dB = smem + (buf) * 8192 + 4096 + wave * 512; \
    GLOAD16(gA0 + (kk), dA); GLOAD16(gA1 + (kk), dA + 2048); \
    GLOAD16(gB0 + (kk), dB); GLOAD16(gB1 + (kk), dB + 2048); }

  STAGE2(0, 0);
  asm volatile("s_waitcnt vmcnt(0)" ::: "memory");
  __builtin_amdgcn_s_barrier();

#pragma unroll
  for (int it = 0; it < 15; it++) {
    const int cur = it & 1, nxt = cur ^ 1;
    STAGE2(nxt, (it + 1) * 32);
    const u16* Ac = smem + cur * 8192;
    const u16* Bc = smem + cur * 8192 + 4096;
    bf16x8 af[4], bf[4];
#pragma unroll
    for (int q = 0; q < 4; q++) {
      af[q] = *(const bf16x8*)(Ac + aoff[q]);
      bf[q] = *(const bf16x8*)(Bc + boff[q]);
    }
#pragma unroll
    for (int i = 0; i < 4; i++)
#pragma unroll
      for (int j = 0; j < 4; j++)
        acc[i][j] = __builtin_amdgcn_mfma_f32_16x16x32_bf16(af[i], bf[j], acc[i][j], 0, 0, 0);
    asm volatile("s_waitcnt vmcnt(0) lgkmcnt(0)" ::: "memory");
    __builtin_amdgcn_s_barrier();
  }
  {
    const u16* Ac = smem + 8192;
    const u16* Bc = smem + 8192 + 4096;
    bf16x8 af[4], bf[4];
#pragma unroll
    for (int q = 0; q < 4; q++) {
      af[q] = *(const bf16x8*)(Ac + aoff[q]);
      bf[q] = *(const bf16x8*)(Bc + boff[q]);
    }
#pragma unroll
    for (int i = 0; i < 4; i++)
#pragma unroll
      for (int j = 0; j < 4; j++)
        acc[i][j] = __builtin_amdgcn_mfma_f32_16x16x32_bf16(af[i], bf[j], acc[i][j], 0, 0, 0);
  }
  asm volatile("s_waitcnt lgkmcnt(0)" ::: "memory");
  __builtin_amdgcn_s_barrier();
#undef STAGE2

#pragma unroll
  for (int half = 0; half < 2; half++) {
    __syncthreads();
    if (wm == half) {
#pragma unroll
      for (int i = 0; i < 4; i++)
#pragma unroll
        for (int r = 0; r < 4; r++) {
          int rrl = i * 16 + qd * 4 + r;
          float bv = bias[m0 + half * 64 + rrl];
#pragma unroll
          for (int j = 0; j < 4; j++)
            Cf[rrl * 133 + wn * 64 + j * 16 + l15] = acc[i][j][r] + bv;
        }
    }
    __syncthreads();
#pragma unroll
    for (int z = 0; z < 2; z++) {
      int rrl = z * 32 + (tid >> 3);
      int seg = tid & 7;
      float* dp = C + (long)(m0 + half * 64 + rrl) * ldc + n0;
      const float* src = Cf + rrl * 133;
#pragma unroll
      for (int p = 0; p < 4; p++)
        *(float4*)(dp + p * 32 + seg * 4) = *(const float4*)(src + p * 32 + seg * 4);
    }
  }
}

// ------------------------------------------------- launch
extern "C" void kernel_launch(void* const* d_in, const int* in_sizes, int n_in,
                              void* d_out, int out_size, void* d_ws, size_t ws_size,
                              hipStream_t stream) {
  const float* x    = (const float*)d_in[0];
  const float* lnw  = (const float*)d_in[1];
  const float* lnb  = (const float*)d_in[2];
  const float* wqkv = (const float*)d_in[3];
  const float* wout = (const float*)d_in[4];
  const float* bout = (const float*)d_in[5];
  float* out = (float*)d_out;
  char* ws = (char*)d_ws;

  u16*  h     = (u16*)(ws + 0L);              // 32 MB (b,n,d) bf16
  u16*  qexp  = (u16*)(ws + 33554432L);       // 32 MB (b,n,512) bf16
  u16*  expkT = (u16*)(ws + 67108864L);       // 32 MB (b,512,n) bf16
  u16*  vT    = (u16*)(ws + 100663296L);      // 32 MB (b,512,n) bf16
  u16*  wqkvT = (u16*)(ws + 134217728L);      // 1.5 MB
  u16*  Mt    = (u16*)(ws + 134217728L);      // 2 MB, reuses wqkvT region (after gemm1)
  float* S    = (float*)(ws + 136314880L);    // 8 KB
  float* ctx  = (float*)(ws + 0L);            // 512 KB, aliases h (dead after gemm1)
  float* Z    = (float*)d_out;                // 1 MB, dead before gemm_tn_f writes out

  hipMemsetAsync(S, 0, 4 * 512 * 4, stream);
  hipMemsetAsync(Z, 0, (long)B_ * NH * 8192 * 4, stream);

  transpose_f2b<<<dim3(24, 8), 256, 0, stream>>>(wqkv, wqkvT, 512, 1536);

  ln_kernel<<<dim3(256, 4), 256, 0, stream>>>(x, lnw, lnb, h);

  gemm1<<<dim3(6, 128), 512, 0, stream>>>(h, wqkvT, qexp, expkT, vT, S, Z);

  zrecip<<<dim3(1024), 256, 0, stream>>>(Z);

  hipMemsetAsync(ctx, 0, 4 * 8 * 64 * 64 * 4, stream);

  ctx_kernel<<<dim3(16, 8, 4), 256, 0, stream>>>(expkT, vT, Z, ctx);

  mprime<<<dim3(8, 8, 4), 256, 0, stream>>>(ctx, wout, S, Mt);

  gemm_tn_f<<<dim3(4, 64, 4), 256, 0, stream>>>(Mt, qexp, out, bout, 512, 8192,
                                                262144L, (long)8192 * 512, (long)512 * 8192);
}

// Round 4
// 324.204 us; speedup vs baseline: 1.0067x; 1.0067x over previous
//
#include <hip/hip_runtime.h>

#define B_   4
#define N_   8192
#define D_   512
#define NH   8
#define DH   64
#define HID  512

typedef unsigned short u16;
typedef __attribute__((ext_vector_type(8))) short  bf16x8;
typedef __attribute__((ext_vector_type(8))) unsigned short u16x8;
typedef __attribute__((ext_vector_type(4))) float  f32x4;

__device__ __forceinline__ float bf2f(u16 u) {
  unsigned int i = ((unsigned int)u) << 16;
  return __builtin_bit_cast(float, i);
}
__device__ __forceinline__ u16 f2bf(float f) {
  unsigned int i = __builtin_bit_cast(unsigned int, f);
  i += 0x7fff + ((i >> 16) & 1);
  return (u16)(i >> 16);
}

#define GLOAD16(g, l) \
  __builtin_amdgcn_global_load_lds((const __attribute__((address_space(1))) void*)(g), \
                                   (__attribute__((address_space(3))) void*)(l), 16, 0, 0)

// ------------------------------------------------- tiled transpose fp32 -> bf16
__global__ __launch_bounds__(256) void transpose_f2b(const float* __restrict__ in,
                                                     u16* __restrict__ out,
                                                     int rows, int cols) {
  __shared__ u16 tile[64][65];
  int c0 = blockIdx.x * 64, r0 = blockIdx.y * 64;
  int t = threadIdx.x;
  int rl = t >> 6, cl = t & 63;
#pragma unroll
  for (int i = 0; i < 16; i++) {
    int r = i * 4 + rl;
    tile[r][cl] = f2bf(in[(long)(r0 + r) * cols + c0 + cl]);
  }
  __syncthreads();
  int c4 = t >> 6, rr = t & 63;
#pragma unroll
  for (int i = 0; i < 16; i++) {
    int c = i * 4 + c4;
    out[(long)(c0 + c) * rows + r0 + rr] = tile[rr][c];
  }
}

// ------------------------------------------------- layernorm, single HBM pass
__global__ __launch_bounds__(256) void ln_kernel(const float* __restrict__ x,
                                                 const float* __restrict__ lw,
                                                 const float* __restrict__ lb,
                                                 u16* __restrict__ h) {
  __shared__ u16 xs[32 * 520];
  __shared__ float red[2][8][32];
  __shared__ float murs[2][32];
  __shared__ float lws[512], lbs[512];
  int b = blockIdx.y, n0 = blockIdx.x * 32;
  int t = threadIdx.x;
  lws[t] = lw[t]; lws[t + 256] = lw[t + 256];
  lbs[t] = lb[t]; lbs[t + 256] = lb[t + 256];
  int tok = t & 31, dp = t >> 5;
  const float* xp = x + (long)b * D_ * N_ + n0 + tok;
  float s = 0.f, s2 = 0.f;
#pragma unroll 8
  for (int i = 0; i < 64; i++) {
    int d = dp * 64 + i;
    float v = xp[(long)d * N_];
    s += v; s2 += v * v;
    xs[tok * 520 + d] = f2bf(v);
  }
  red[0][dp][tok] = s; red[1][dp][tok] = s2;
  __syncthreads();
  if (t < 32) {
    float S1 = 0.f, S2 = 0.f;
#pragma unroll
    for (int i = 0; i < 8; i++) { S1 += red[0][i][t]; S2 += red[1][i][t]; }
    float mu = S1 * (1.0f / 512.0f);
    float var = S2 * (1.0f / 512.0f) - mu * mu;
    murs[0][t] = mu; murs[1][t] = rsqrtf(var + 1e-5f);
  }
  __syncthreads();
  int row = t >> 3, seg = t & 7;
  float mu = murs[0][row], rs = murs[1][row];
  u16* hp = h + ((long)b * N_ + n0 + row) * D_;
  const u16* xr = xs + row * 520;
#pragma unroll
  for (int c = 0; c < 8; c++) {
    int d0 = c * 64 + seg * 8;
    u16x8 in8 = *(const u16x8*)(xr + d0);
    u16x8 o;
#pragma unroll
    for (int i = 0; i < 8; i++) {
      int d = d0 + i;
      o[i] = f2bf((bf2f(in8[i]) - mu) * rs * lws[d] + lbs[d]);
    }
    *(u16x8*)(hp + d0) = o;
  }
}

// ------------------------------------------------- GEMM1: 256x256 tile, BK=64, 8 waves,
// counted-vmcnt multi-phase pipeline (T3+T4), LDS XOR-swizzle (T2), setprio (T5),
// XCD-chunked swizzle (T1). Fused exp/S/Z epilogue with 3-way stores.
// NOTE: no min-waves clamp in launch_bounds — acc alone is 128 VGPRs; clamping to
// 2 waves/EU (<=128 VGPR) spills acc to scratch (R3 regression: +120MB HBM, 17% MfmaUtil).
// Occupancy is LDS-capped at 1 block/CU (= 2 waves/SIMD) regardless, so no clamp needed.
__global__ __launch_bounds__(512) void gemm1(const u16* __restrict__ A,
                                             const u16* __restrict__ B,
                                             u16* __restrict__ qexp,
                                             u16* __restrict__ expkT,
                                             u16* __restrict__ vT,
                                             float* __restrict__ S,
                                             float* __restrict__ Z) {
  // LDS map (u16 units): A[buf][256][64] @ 0 (buf stride 16384), B[buf][256][64] @ 32768.
  // Swizzle: 16B slot s at row r holds global slot s ^ (r&7).
  __shared__ alignas(16) u16 smem[65536];   // 128 KiB

  // XCD swizzle: nwg = 768 (6 x 128), 96 contiguous work-ids per XCD.
  int bid = blockIdx.y * 6 + blockIdx.x;
  int wid = (bid & 7) * 96 + (bid >> 3);
  int bx = wid % 6, by = wid / 6;
  int m0 = by * 256, n0 = bx * 256;

  int tid = threadIdx.x, w = tid >> 6, lane = tid & 63;
  int l15 = lane & 15, qd = lane >> 4;
  int wm = w >> 2, wn = w & 3;              // wave tile: rows [wm*128,+128), cols [wn*64,+64)

  // ---- staging geometry: one half = 128 rows x 64 cols; per wave 2 gload16 (q=0,1)
  int rl = lane >> 3;                        // 0..7
  int sg8 = ((lane & 7) ^ rl) * 8;           // inverse-swizzled global 16B-slot (u16 units)
  int ofsA[2][2], ofsB[2][2];                // [q][hs] row offsets * 512 (K)
#pragma unroll
  for (int q = 0; q < 2; q++)
#pragma unroll
    for (int hs = 0; hs < 2; hs++) {
      int r = hs * 128 + (w * 2 + q) * 8 + rl;
      ofsA[q][hs] = (m0 + r) * 512;
      ofsB[q][hs] = (n0 + r) * 512;
    }
  const u16* Ag = A + sg8;
  const u16* Bg = B + sg8;

  // ---- fragment read bases (swizzled)
  int baseA = (wm * 128 + l15) * 64 + ((qd ^ (l15 & 7)) * 8);
  int baseB = (wn * 64 + l15) * 64 + ((qd ^ (l15 & 7)) * 8);

  f32x4 zero = {0.f, 0.f, 0.f, 0.f};
  f32x4 acc[8][4];
#pragma unroll
  for (int i = 0; i < 8; i++)
#pragma unroll
    for (int j = 0; j < 4; j++) acc[i][j] = zero;

#define STG_A(buf, hs, kt) { \
    GLOAD16(Ag + ofsA[0][hs] + (kt) * 64, smem + (buf) * 16384 + (hs) * 8192 + (w * 2 + 0) * 512); \
    GLOAD16(Ag + ofsA[1][hs] + (kt) * 64, smem + (buf) * 16384 + (hs) * 8192 + (w * 2 + 1) * 512); }
#define STG_B(buf, hs, kt) { \
    GLOAD16(Bg + ofsB[0][hs] + (kt) * 64, smem + 32768 + (buf) * 16384 + (hs) * 8192 + (w * 2 + 0) * 512); \
    GLOAD16(Bg + ofsB[1][hs] + (kt) * 64, smem + 32768 + (buf) * 16384 + (hs) * 8192 + (w * 2 + 1) * 512); }

  // prologue: A(0), B(0), A(1)  (12 loads/wave); A(1) may stay in flight
  STG_A(0, 0, 0); STG_A(0, 1, 0);
  STG_B(0, 0, 0); STG_B(0, 1, 0);
  STG_A(1, 0, 1); STG_A(1, 1, 1);
  asm volatile("s_waitcnt vmcnt(4)" ::: "memory");
  __builtin_amdgcn_s_barrier();

#pragma unroll
  for (int tt = 0; tt < 8; tt++) {
    const int c = tt & 1;
    const u16* Ab = smem + c * 16384;
    const u16* Bb = smem + 32768 + c * 16384;
    bf16x8 aL[4][2], aH[4][2], bb[4][2];
    // ---- P0: read A-low + all B; MFMA m0-3 x n0-1
#pragma unroll
    for (int i = 0; i < 4; i++)
#pragma unroll
      for (int ks = 0; ks < 2; ks++)
        aL[i][ks] = *(const bf16x8*)(Ab + ((baseA + i * 1024) ^ (ks * 32)));
#pragma unroll
    for (int j = 0; j < 4; j++)
#pragma unroll
      for (int ks = 0; ks < 2; ks++)
        bb[j][ks] = *(const bf16x8*)(Bb + ((baseB + j * 1024) ^ (ks * 32)));
    __builtin_amdgcn_s_setprio(1);
#pragma unroll
    for (int i = 0; i < 4; i++)
#pragma unroll
      for (int j = 0; j < 2; j++)
#pragma unroll
        for (int ks = 0; ks < 2; ks++)
          acc[i][j] = __builtin_amdgcn_mfma_f32_16x16x32_bf16(aL[i][ks], bb[j][ks], acc[i][j], 0, 0, 0);
    __builtin_amdgcn_s_setprio(0);
    __builtin_amdgcn_s_barrier();
    // ---- P1: read A-high; stage B(tt+1) into buf c^1 (B slots dead since P0); MFMA m4-7 x n0-1
#pragma unroll
    for (int i = 0; i < 4; i++)
#pragma unroll
      for (int ks = 0; ks < 2; ks++)
        aH[i][ks] = *(const bf16x8*)(Ab + ((baseA + (4 + i) * 1024) ^ (ks * 32)));
    if (tt < 7) { STG_B(c ^ 1, 0, tt + 1); STG_B(c ^ 1, 1, tt + 1); }
    __builtin_amdgcn_s_setprio(1);
#pragma unroll
    for (int i = 0; i < 4; i++)
#pragma unroll
      for (int j = 0; j < 2; j++)
#pragma unroll
        for (int ks = 0; ks < 2; ks++)
          acc[4 + i][j] = __builtin_amdgcn_mfma_f32_16x16x32_bf16(aH[i][ks], bb[j][ks], acc[4 + i][j], 0, 0, 0);
    __builtin_amdgcn_s_setprio(0);
    __builtin_amdgcn_s_barrier();
    // ---- P2: stage A(tt+2) into buf c (A slots dead since P1); MFMA m0-7 x n2-3; counted vmcnt
    if (tt < 6) { STG_A(c, 0, tt + 2); STG_A(c, 1, tt + 2); }
    __builtin_amdgcn_s_setprio(1);
#pragma unroll
    for (int i = 0; i < 4; i++)
#pragma unroll
      for (int j = 2; j < 4; j++)
#pragma unroll
        for (int ks = 0; ks < 2; ks++)
          acc[i][j] = __builtin_amdgcn_mfma_f32_16x16x32_bf16(aL[i][ks], bb[j][ks], acc[i][j], 0, 0, 0);
#pragma unroll
    for (int i = 0; i < 4; i++)
#pragma unroll
      for (int j = 2; j < 4; j++)
#pragma unroll
        for (int ks = 0; ks < 2; ks++)
          acc[4 + i][j] = __builtin_amdgcn_mfma_f32_16x16x32_bf16(aH[i][ks], bb[j][ks], acc[4 + i][j], 0, 0, 0);
    __builtin_amdgcn_s_setprio(0);
    if (tt < 6) { asm volatile("s_waitcnt vmcnt(4)" ::: "memory"); }
    else        { asm volatile("s_waitcnt vmcnt(0)" ::: "memory"); }
    __builtin_amdgcn_s_barrier();
  }
#undef STG_A
#undef STG_B

  // ---------------- fused epilogue
  int third = n0 >> 9;
  int n0t = n0 & 511;
  int b = m0 >> 13;
  int tloc = m0 & 8191;

  if (third == 0) {
#pragma unroll
    for (int i = 0; i < 8; i++)
#pragma unroll
      for (int j = 0; j < 4; j++)
#pragma unroll
        for (int r = 0; r < 4; r++) acc[i][j][r] = __expf(acc[i][j][r] * 0.125f);
    // column sums -> S (softmax over tokens denominators)
#pragma unroll
    for (int j = 0; j < 4; j++) {
      float ps = 0.f;
#pragma unroll
      for (int i = 0; i < 8; i++)
#pragma unroll
        for (int r = 0; r < 4; r++) ps += acc[i][j][r];
      ps += __shfl_xor(ps, 16);
      ps += __shfl_xor(ps, 32);
      if (qd == 0) atomicAdd(S + b * 512 + n0t + wn * 64 + j * 16 + l15, ps);
    }
  } else if (third == 1) {
#pragma unroll
    for (int i = 0; i < 8; i++)
#pragma unroll
      for (int j = 0; j < 4; j++)
#pragma unroll
        for (int r = 0; r < 4; r++) acc[i][j][r] = __expf(acc[i][j][r]);
    int head = (n0t >> 6) + wn;
#pragma unroll
    for (int i = 0; i < 8; i++)
#pragma unroll
      for (int r = 0; r < 4; r++) {
        float rs = acc[i][0][r] + acc[i][1][r] + acc[i][2][r] + acc[i][3][r];
        rs += __shfl_xor(rs, 1);
        rs += __shfl_xor(rs, 2);
        rs += __shfl_xor(rs, 4);
        rs += __shfl_xor(rs, 8);
        if (l15 == 0)
          atomicAdd(Z + ((long)b * NH + head) * 8192 + tloc + wm * 128 + i * 16 + qd * 4 + r, rs);
      }
  }

  // stores via LDS restage (aliases staging buffers), two 128-row halves
  u16* Cs = smem;
  if (third == 0) {
    u16* dstb = qexp + ((long)b * 8192 + tloc) * 512 + n0t;
#pragma unroll
    for (int hh = 0; hh < 2; hh++) {
      if (hh) __syncthreads();
      if (wm == hh) {
#pragma unroll
        for (int i = 0; i < 8; i++)
#pragma unroll
          for (int r = 0; r < 4; r++)
#pragma unroll
            for (int j = 0; j < 4; j++)
              Cs[(i * 16 + qd * 4 + r) * 264 + wn * 64 + j * 16 + l15] = f2bf(acc[i][j][r]);
      }
      __syncthreads();
      u16* dst = dstb + (long)hh * 128 * 512;
#pragma unroll
      for (int z = 0; z < 8; z++) {
        int row = z * 16 + (tid >> 5);
        int off = (tid & 31) * 8;
        *(uint4*)(dst + (long)row * 512 + off) = *(const uint4*)(Cs + row * 264 + off);
      }
    }
  } else {
    u16* dstb = (third == 1 ? expkT : vT) + ((long)b * 512 + n0t) * 8192 + tloc;
#pragma unroll
    for (int hh = 0; hh < 2; hh++) {
      if (hh) __syncthreads();
      if (wm == hh) {
#pragma unroll
        for (int i = 0; i < 8; i++)
#pragma unroll
          for (int r = 0; r < 4; r++)
#pragma unroll
            for (int j = 0; j < 4; j++)
              Cs[(wn * 64 + j * 16 + l15) * 136 + i * 16 + qd * 4 + r] = f2bf(acc[i][j][r]);
      }
      __syncthreads();
#pragma unroll
      for (int z = 0; z < 8; z++) {
        int col = z * 32 + (tid >> 4);
        int moff = (tid & 15) * 8;
        *(uint4*)(dstb + (long)col * 8192 + hh * 128 + moff) = *(const uint4*)(Cs + col * 136 + moff);
      }
    }
  }
}

// ------------------------------------------------- Z -> 1/Z
__global__ __launch_bounds__(256) void zrecip(float* __restrict__ Z) {
  int i = blockIdx.x * 256 + threadIdx.x;
  Z[i] = 1.0f / Z[i];
}

// ------------------------------------------------- ctx[b,h,d,e] += sum_n expkT[d,n] * vT[e,n] * Zr[b,h,n]
__global__ __launch_bounds__(256) void ctx_kernel(const u16* __restrict__ expkT,
                                                  const u16* __restrict__ vT,
                                                  const float* __restrict__ Zr,
                                                  float* __restrict__ ctx) {
  __shared__ u16 As[64 * 128];
  __shared__ u16 Bs[64 * 128];
  int kc = blockIdx.x, hh = blockIdx.y, b = blockIdx.z;
  int t = threadIdx.x, w = t >> 6, l = t & 63, l15 = l & 15, qd = l >> 4;
  long nbase = (long)kc * 512;
  const u16* Abase = expkT + ((long)b * 512 + hh * 64) * 8192 + nbase;
  const u16* Bbase = vT   + ((long)b * 512 + hh * 64) * 8192 + nbase;
  const float* Zb = Zr + ((long)b * NH + hh) * 8192 + nbase;

  f32x4 zero = {0.f, 0.f, 0.f, 0.f};
  f32x4 acc[4] = {zero, zero, zero, zero};

  int brow = t >> 2;
  for (int s = 0; s < 4; s++) {
    long ko = (long)s * 128;
    __syncthreads();
#pragma unroll
    for (int si = 0; si < 4; si++) {
      int qq = si * 4 + w;
      int row = qq * 4 + (l >> 4);
      int gs = (l & 15) ^ (row & 15);
      GLOAD16(Abase + (long)row * 8192 + ko + gs * 8, As + qq * 512);
    }
    {
      const u16* src = Bbase + (long)brow * 8192 + ko;
#pragma unroll
      for (int cc = 0; cc < 4; cc++) {
        int c = (t & 3) * 4 + cc;
        u16x8 v8 = *(const u16x8*)(src + c * 8);
        float4 z0 = *(const float4*)(Zb + ko + c * 8);
        float4 z1 = *(const float4*)(Zb + ko + c * 8 + 4);
        u16x8 o;
        o[0] = f2bf(bf2f(v8[0]) * z0.x); o[1] = f2bf(bf2f(v8[1]) * z0.y);
        o[2] = f2bf(bf2f(v8[2]) * z0.z); o[3] = f2bf(bf2f(v8[3]) * z0.w);
        o[4] = f2bf(bf2f(v8[4]) * z1.x); o[5] = f2bf(bf2f(v8[5]) * z1.y);
        o[6] = f2bf(bf2f(v8[6]) * z1.z); o[7] = f2bf(bf2f(v8[7]) * z1.w);
        *(u16x8*)(Bs + brow * 128 + ((c ^ (brow & 15)) * 8)) = o;
      }
    }
    __syncthreads();
#pragma unroll
    for (int kk = 0; kk < 4; kk++) {
      int ar = w * 16 + l15;
      bf16x8 af = *(const bf16x8*)(As + ar * 128 + (((kk * 4 + qd) ^ (ar & 15)) * 8));
#pragma unroll
      for (int j = 0; j < 4; j++) {
        int br = j * 16 + l15;
        bf16x8 bf8 = *(const bf16x8*)(Bs + br * 128 + (((kk * 4 + qd) ^ (br & 15)) * 8));
        acc[j] = __builtin_amdgcn_mfma_f32_16x16x32_bf16(af, bf8, acc[j], 0, 0, 0);
      }
    }
  }
  float* cp = ctx + ((long)(b * NH + hh)) * DH * DH;
#pragma unroll
  for (int j = 0; j < 4; j++)
#pragma unroll
    for (int r = 0; r < 4; r++)
      atomicAdd(cp + (w * 16 + qd * 4 + r) * 64 + j * 16 + l15, acc[j][r]);
}

// ------------------------------------------------- mprime
__global__ __launch_bounds__(256) void mprime(const float* __restrict__ ctx,
                                              const float* __restrict__ wout,
                                              const float* __restrict__ S,
                                              u16* __restrict__ Mt) {
  __shared__ float ws[64 * 65];
  __shared__ float cs[64 * 65];
  int dt = blockIdx.x, hh = blockIdx.y, b = blockIdx.z;
  int t = threadIdx.x;
  {
    int e = t >> 2;
#pragma unroll
    for (int ii = 0; ii < 4; ii++) {
      int col = (t & 3) * 16 + ii * 4;
      float4 v = *(const float4*)(wout + (long)(hh * 64 + e) * 512 + dt * 64 + col);
      ws[e * 65 + col] = v.x; ws[e * 65 + col + 1] = v.y;
      ws[e * 65 + col + 2] = v.z; ws[e * 65 + col + 3] = v.w;
      float4 c = *(const float4*)(ctx + ((long)(b * NH + hh)) * 4096 + (long)e * 64 + col);
      cs[e * 65 + col] = c.x; cs[e * 65 + col + 1] = c.y;
      cs[e * 65 + col + 2] = c.z; cs[e * 65 + col + 3] = c.w;
    }
  }
  __syncthreads();
  int dol = t & 63, dg = t >> 6;
#pragma unroll
  for (int dd = 0; dd < 16; dd++) {
    int d = dg * 16 + dd;
    float v = 0.f;
#pragma unroll 8
    for (int e = 0; e < 64; e++) v += cs[d * 65 + e] * ws[e * 65 + dol];
    float sv = S[b * 512 + hh * 64 + d];
    Mt[(long)b * 262144 + (long)(dt * 64 + dol) * 512 + hh * 64 + d] = f2bf(v / sv);
  }
}

// ------------------------------------------------- GEMM2 (TN), fp32 out + bias
__global__ __launch_bounds__(256) void gemm_tn_f(const u16* __restrict__ A,
                                                 const u16* __restrict__ B,
                                                 float* __restrict__ C,
                                                 const float* __restrict__ bias,
                                                 int K, int ldc,
                                                 long sA, long sB, long sC) {
  __shared__ alignas(16) u16 smem[17408];
  float* Cf = (float*)smem;

  int bid = (blockIdx.z * gridDim.y + blockIdx.y) * gridDim.x + blockIdx.x;
  int wid = (bid & 7) * 128 + (bid >> 3);
  int mx = wid & 3;
  int ny = (wid >> 2) & 63;
  long bz = wid >> 8;
  A += bz * sA; B += bz * sB; C += bz * sC;
  int m0 = mx * 128, n0 = ny * 128;

  int tid = threadIdx.x, wave = tid >> 6, lane = tid & 63;
  int l15 = lane & 15, qd = lane >> 4;

  int ra0 = tid >> 2,          qa0 = (tid & 3) ^ ((ra0 >> 1) & 3);
  int ra1 = (tid + 256) >> 2,  qa1 = (tid & 3) ^ ((ra1 >> 1) & 3);
  const u16* gA0 = A + (long)(m0 + ra0) * K + qa0 * 8;
  const u16* gA1 = A + (long)(m0 + ra1) * K + qa1 * 8;
  const u16* gB0 = B + (long)(n0 + ra0) * K + qa0 * 8;
  const u16* gB1 = B + (long)(n0 + ra1) * K + qa1 * 8;

  int wm = wave & 1, wn = wave >> 1;
  int aoff[4], boff[4];
#pragma unroll
  for (int i = 0; i < 4; i++) {
    int r = wm * 64 + i * 16 + l15;
    aoff[i] = r * 32 + ((qd ^ ((r >> 1) & 3)) * 8);
    int rb = wn * 64 + i * 16 + l15;
    boff[i] = rb * 32 + ((qd ^ ((rb >> 1) & 3)) * 8);
  }

  f32x4 zero = {0.f, 0.f, 0.f, 0.f};
  f32x4 acc[4][4];
#pragma unroll
  for (int i = 0; i < 4; i++)
#pragma unroll
    for (int j = 0; j < 4; j++) acc[i][j] = zero;

#define STAGE2(buf, kk) { \
    u16* dA = smem + (buf) * 8192 + wave * 512; \
    u16* dB = smem + (buf) * 8192 + 4096 + wave * 512; \
    GLOAD16(gA0 + (kk), dA); GLOAD16(gA1 + (kk), dA + 2048); \
    GLOAD16(gB0 + (kk), dB); GLOAD16(gB1 + (kk), dB + 2048); }

  STAGE2(0, 0);
  asm volatile("s_waitcnt vmcnt(0)" ::: "memory");
  __builtin_amdgcn_s_barrier();

#pragma unroll
  for (int it = 0; it < 15; it++) {
    const int cur = it & 1, nxt = cur ^ 1;
    STAGE2(nxt, (it + 1) * 32);
    const u16* Ac = smem + cur * 8192;
    const u16* Bc = smem + cur * 8192 + 4096;
    bf16x8 af[4], bf[4];
#pragma unroll
    for (int q = 0; q < 4; q++) {
      af[q] = *(const bf16x8*)(Ac + aoff[q]);
      bf[q] = *(const bf16x8*)(Bc + boff[q]);
    }
#pragma unroll
    for (int i = 0; i < 4; i++)
#pragma unroll
      for (int j = 0; j < 4; j++)
        acc[i][j] = __builtin_amdgcn_mfma_f32_16x16x32_bf16(af[i], bf[j], acc[i][j], 0, 0, 0);
    asm volatile("s_waitcnt vmcnt(0) lgkmcnt(0)" ::: "memory");
    __builtin_amdgcn_s_barrier();
  }
  {
    const u16* Ac = smem + 8192;
    const u16* Bc = smem + 8192 + 4096;
    bf16x8 af[4], bf[4];
#pragma unroll
    for (int q = 0; q < 4; q++) {
      af[q] = *(const bf16x8*)(Ac + aoff[q]);
      bf[q] = *(const bf16x8*)(Bc + boff[q]);
    }
#pragma unroll
    for (int i = 0; i < 4; i++)
#pragma unroll
      for (int j = 0; j < 4; j++)
        acc[i][j] = __builtin_amdgcn_mfma_f32_16x16x32_bf16(af[i], bf[j], acc[i][j], 0, 0, 0);
  }
  asm volatile("s_waitcnt lgkmcnt(0)" ::: "memory");
  __builtin_amdgcn_s_barrier();
#undef STAGE2

#pragma unroll
  for (int half = 0; half < 2; half++) {
    __syncthreads();
    if (wm == half) {
#pragma unroll
      for (int i = 0; i < 4; i++)
#pragma unroll
        for (int r = 0; r < 4; r++) {
          int rrl = i * 16 + qd * 4 + r;
          float bv = bias[m0 + half * 64 + rrl];
#pragma unroll
          for (int j = 0; j < 4; j++)
            Cf[rrl * 133 + wn * 64 + j * 16 + l15] = acc[i][j][r] + bv;
        }
    }
    __syncthreads();
#pragma unroll
    for (int z = 0; z < 2; z++) {
      int rrl = z * 32 + (tid >> 3);
      int seg = tid & 7;
      float* dp = C + (long)(m0 + half * 64 + rrl) * ldc + n0;
      const float* src = Cf + rrl * 133;
#pragma unroll
      for (int p = 0; p < 4; p++)
        *(float4*)(dp + p * 32 + seg * 4) = *(const float4*)(src + p * 32 + seg * 4);
    }
  }
}

// ------------------------------------------------- launch
extern "C" void kernel_launch(void* const* d_in, const int* in_sizes, int n_in,
                              void* d_out, int out_size, void* d_ws, size_t ws_size,
                              hipStream_t stream) {
  const float* x    = (const float*)d_in[0];
  const float* lnw  = (const float*)d_in[1];
  const float* lnb  = (const float*)d_in[2];
  const float* wqkv = (const float*)d_in[3];
  const float* wout = (const float*)d_in[4];
  const float* bout = (const float*)d_in[5];
  float* out = (float*)d_out;
  char* ws = (char*)d_ws;

  u16*  h     = (u16*)(ws + 0L);              // 32 MB (b,n,d) bf16
  u16*  qexp  = (u16*)(ws + 33554432L);       // 32 MB (b,n,512) bf16
  u16*  expkT = (u16*)(ws + 67108864L);       // 32 MB (b,512,n) bf16
  u16*  vT    = (u16*)(ws + 100663296L);      // 32 MB (b,512,n) bf16
  u16*  wqkvT = (u16*)(ws + 134217728L);      // 1.5 MB
  u16*  Mt    = (u16*)(ws + 134217728L);      // 2 MB, reuses wqkvT region (after gemm1)
  float* S    = (float*)(ws + 136314880L);    // 8 KB
  float* ctx  = (float*)(ws + 0L);            // 512 KB, aliases h (dead after gemm1)
  float* Z    = (float*)d_out;                // 1 MB, dead before gemm_tn_f writes out

  hipMemsetAsync(S, 0, 4 * 512 * 4, stream);
  hipMemsetAsync(Z, 0, (long)B_ * NH * 8192 * 4, stream);

  transpose_f2b<<<dim3(24, 8), 256, 0, stream>>>(wqkv, wqkvT, 512, 1536);

  ln_kernel<<<dim3(256, 4), 256, 0, stream>>>(x, lnw, lnb, h);

  gemm1<<<dim3(6, 128), 512, 0, stream>>>(h, wqkvT, qexp, expkT, vT, S, Z);

  zrecip<<<dim3(1024), 256, 0, stream>>>(Z);

  hipMemsetAsync(ctx, 0, 4 * 8 * 64 * 64 * 4, stream);

  ctx_kernel<<<dim3(16, 8, 4), 256, 0, stream>>>(expkT, vT, Z, ctx);

  mprime<<<dim3(8, 8, 4), 256, 0, stream>>>(ctx, wout, S, Mt);

  gemm_tn_f<<<dim3(4, 64, 4), 256, 0, stream>>>(Mt, qexp, out, bout, 512, 8192,
                                                262144L, (long)8192 * 512, (long)512 * 8192);
}

// Round 5
// 311.177 us; speedup vs baseline: 1.0488x; 1.0419x over previous
//
#include <hip/hip_runtime.h>

#define B_   4
#define N_   8192
#define D_   512
#define NH   8
#define DH   64
#define HID  512

typedef unsigned short u16;
typedef __attribute__((ext_vector_type(8))) short  bf16x8;
typedef __attribute__((ext_vector_type(8))) unsigned short u16x8;
typedef __attribute__((ext_vector_type(4))) float  f32x4;

__device__ __forceinline__ float bf2f(u16 u) {
  unsigned int i = ((unsigned int)u) << 16;
  return __builtin_bit_cast(float, i);
}
__device__ __forceinline__ u16 f2bf(float f) {
  unsigned int i = __builtin_bit_cast(unsigned int, f);
  i += 0x7fff + ((i >> 16) & 1);
  return (u16)(i >> 16);
}

#define GLOAD16(g, l) \
  __builtin_amdgcn_global_load_lds((const __attribute__((address_space(1))) void*)(g), \
                                   (__attribute__((address_space(3))) void*)(l), 16, 0, 0)

// ------------------------------------------------- tiled transpose fp32 -> bf16
__global__ __launch_bounds__(256) void transpose_f2b(const float* __restrict__ in,
                                                     u16* __restrict__ out,
                                                     int rows, int cols) {
  __shared__ u16 tile[64][65];
  int c0 = blockIdx.x * 64, r0 = blockIdx.y * 64;
  int t = threadIdx.x;
  int rl = t >> 6, cl = t & 63;
#pragma unroll
  for (int i = 0; i < 16; i++) {
    int r = i * 4 + rl;
    tile[r][cl] = f2bf(in[(long)(r0 + r) * cols + c0 + cl]);
  }
  __syncthreads();
  int c4 = t >> 6, rr = t & 63;
#pragma unroll
  for (int i = 0; i < 16; i++) {
    int c = i * 4 + c4;
    out[(long)(c0 + c) * rows + r0 + rr] = tile[rr][c];
  }
}

// ------------------------------------------------- layernorm, single HBM pass
__global__ __launch_bounds__(256) void ln_kernel(const float* __restrict__ x,
                                                 const float* __restrict__ lw,
                                                 const float* __restrict__ lb,
                                                 u16* __restrict__ h) {
  __shared__ u16 xs[32 * 520];
  __shared__ float red[2][8][32];
  __shared__ float murs[2][32];
  __shared__ float lws[512], lbs[512];
  int b = blockIdx.y, n0 = blockIdx.x * 32;
  int t = threadIdx.x;
  lws[t] = lw[t]; lws[t + 256] = lw[t + 256];
  lbs[t] = lb[t]; lbs[t + 256] = lb[t + 256];
  int tok = t & 31, dp = t >> 5;
  const float* xp = x + (long)b * D_ * N_ + n0 + tok;
  float s = 0.f, s2 = 0.f;
#pragma unroll 8
  for (int i = 0; i < 64; i++) {
    int d = dp * 64 + i;
    float v = xp[(long)d * N_];
    s += v; s2 += v * v;
    xs[tok * 520 + d] = f2bf(v);
  }
  red[0][dp][tok] = s; red[1][dp][tok] = s2;
  __syncthreads();
  if (t < 32) {
    float S1 = 0.f, S2 = 0.f;
#pragma unroll
    for (int i = 0; i < 8; i++) { S1 += red[0][i][t]; S2 += red[1][i][t]; }
    float mu = S1 * (1.0f / 512.0f);
    float var = S2 * (1.0f / 512.0f) - mu * mu;
    murs[0][t] = mu; murs[1][t] = rsqrtf(var + 1e-5f);
  }
  __syncthreads();
  int row = t >> 3, seg = t & 7;
  float mu = murs[0][row], rs = murs[1][row];
  u16* hp = h + ((long)b * N_ + n0 + row) * D_;
  const u16* xr = xs + row * 520;
#pragma unroll
  for (int c = 0; c < 8; c++) {
    int d0 = c * 64 + seg * 8;
    u16x8 in8 = *(const u16x8*)(xr + d0);
    u16x8 o;
#pragma unroll
    for (int i = 0; i < 8; i++) {
      int d = d0 + i;
      o[i] = f2bf((bf2f(in8[i]) - mu) * rs * lws[d] + lbs[d]);
    }
    *(u16x8*)(hp + d0) = o;
  }
}

// ------------------------------------------------- GEMM1: 256x256 tile, BK=64, 8 waves,
// counted-vmcnt pipeline (T3+T4), LDS XOR-swizzle (T2), setprio (T5), XCD swizzle (T1).
// Quadrant-phase K-loop: peak fragment liveness 64 VGPRs (a[4][2] reused across halves,
// b0/b1 16 each) so acc(128, AGPR) + frags + addressing fits without scratch spills.
// R3/R4 lesson: holding all-B + both A halves (96 regs) spilled ~128MB/dispatch to scratch.
// launch_bounds(512,1): LDS caps occupancy at 1 block/CU anyway; allow full VGPR budget.
__global__ __launch_bounds__(512, 1) void gemm1(const u16* __restrict__ A,
                                                const u16* __restrict__ B,
                                                u16* __restrict__ qexp,
                                                u16* __restrict__ expkT,
                                                u16* __restrict__ vT,
                                                float* __restrict__ S,
                                                float* __restrict__ Z) {
  // LDS map (u16 units): A[buf][256][64] @ 0 (buf stride 16384), B[buf][256][64] @ 32768.
  // Swizzle: 16B slot s at row r holds global slot s ^ (r&7).
  __shared__ alignas(16) u16 smem[65536];   // 128 KiB

  // XCD swizzle: nwg = 768 (6 x 128), 96 contiguous work-ids per XCD.
  int bid = blockIdx.y * 6 + blockIdx.x;
  int wid = (bid & 7) * 96 + (bid >> 3);
  int bx = wid % 6, by = wid / 6;
  int m0 = by * 256, n0 = bx * 256;

  int tid = threadIdx.x, w = tid >> 6, lane = tid & 63;
  int l15 = lane & 15, qd = lane >> 4;
  int wm = w >> 2, wn = w & 3;              // wave tile: rows [wm*128,+128), cols [wn*64,+64)

  // ---- staging geometry: one half = 128 rows x 64 cols; per wave 2 gload16 (q=0,1)
  int rl = lane >> 3;                        // 0..7
  int sg8 = ((lane & 7) ^ rl) * 8;           // inverse-swizzled global 16B-slot (u16 units)
  int ofsA[2][2], ofsB[2][2];                // [q][hs] row offsets * 512 (K)
#pragma unroll
  for (int q = 0; q < 2; q++)
#pragma unroll
    for (int hs = 0; hs < 2; hs++) {
      int r = hs * 128 + (w * 2 + q) * 8 + rl;
      ofsA[q][hs] = (m0 + r) * 512;
      ofsB[q][hs] = (n0 + r) * 512;
    }
  const u16* Ag = A + sg8;
  const u16* Bg = B + sg8;

  // ---- fragment read bases (swizzled)
  int baseA = (wm * 128 + l15) * 64 + ((qd ^ (l15 & 7)) * 8);
  int baseB = (wn * 64 + l15) * 64 + ((qd ^ (l15 & 7)) * 8);

  f32x4 zero = {0.f, 0.f, 0.f, 0.f};
  f32x4 acc[8][4];
#pragma unroll
  for (int i = 0; i < 8; i++)
#pragma unroll
    for (int j = 0; j < 4; j++) acc[i][j] = zero;

#define STG_A(buf, hs, kt) { \
    GLOAD16(Ag + ofsA[0][hs] + (kt) * 64, smem + (buf) * 16384 + (hs) * 8192 + (w * 2 + 0) * 512); \
    GLOAD16(Ag + ofsA[1][hs] + (kt) * 64, smem + (buf) * 16384 + (hs) * 8192 + (w * 2 + 1) * 512); }
#define STG_B(buf, hs, kt) { \
    GLOAD16(Bg + ofsB[0][hs] + (kt) * 64, smem + 32768 + (buf) * 16384 + (hs) * 8192 + (w * 2 + 0) * 512); \
    GLOAD16(Bg + ofsB[1][hs] + (kt) * 64, smem + 32768 + (buf) * 16384 + (hs) * 8192 + (w * 2 + 1) * 512); }

  // prologue: A(0), B(0), A(1)  (12 loads/wave); A(1) may stay in flight
  STG_A(0, 0, 0); STG_A(0, 1, 0);
  STG_B(0, 0, 0); STG_B(0, 1, 0);
  STG_A(1, 0, 1); STG_A(1, 1, 1);
  asm volatile("s_waitcnt vmcnt(4)" ::: "memory");
  __builtin_amdgcn_s_barrier();

#pragma unroll
  for (int tt = 0; tt < 8; tt++) {
    const int c = tt & 1;
    const u16* Ab = smem + c * 16384;
    const u16* Bb = smem + 32768 + c * 16384;
    bf16x8 a[4][2], b0[2][2], b1[2][2];
    // ---- P0: read a-low + b-low; stage B(tt+1) into buf c^1; MFMA (i0-3, j0-1)
#pragma unroll
    for (int i = 0; i < 4; i++)
#pragma unroll
      for (int ks = 0; ks < 2; ks++)
        a[i][ks] = *(const bf16x8*)(Ab + ((baseA + i * 1024) ^ (ks * 32)));
#pragma unroll
    for (int j = 0; j < 2; j++)
#pragma unroll
      for (int ks = 0; ks < 2; ks++)
        b0[j][ks] = *(const bf16x8*)(Bb + ((baseB + j * 1024) ^ (ks * 32)));
    if (tt < 7) { STG_B(c ^ 1, 0, tt + 1); STG_B(c ^ 1, 1, tt + 1); }
    __builtin_amdgcn_s_setprio(1);
#pragma unroll
    for (int i = 0; i < 4; i++)
#pragma unroll
      for (int j = 0; j < 2; j++)
#pragma unroll
        for (int ks = 0; ks < 2; ks++)
          acc[i][j] = __builtin_amdgcn_mfma_f32_16x16x32_bf16(a[i][ks], b0[j][ks], acc[i][j], 0, 0, 0);
    __builtin_amdgcn_s_setprio(0);
    // ---- P1: read b-high; MFMA (i0-3, j2-3)
#pragma unroll
    for (int j = 0; j < 2; j++)
#pragma unroll
      for (int ks = 0; ks < 2; ks++)
        b1[j][ks] = *(const bf16x8*)(Bb + ((baseB + (2 + j) * 1024) ^ (ks * 32)));
    __builtin_amdgcn_s_setprio(1);
#pragma unroll
    for (int i = 0; i < 4; i++)
#pragma unroll
      for (int j = 0; j < 2; j++)
#pragma unroll
        for (int ks = 0; ks < 2; ks++)
          acc[i][2 + j] = __builtin_amdgcn_mfma_f32_16x16x32_bf16(a[i][ks], b1[j][ks], acc[i][2 + j], 0, 0, 0);
    __builtin_amdgcn_s_setprio(0);
    // ---- P2: read a-high (reuse a[] regs -> peak liveness 64); MFMA (i4-7, j0-1)
#pragma unroll
    for (int i = 0; i < 4; i++)
#pragma unroll
      for (int ks = 0; ks < 2; ks++)
        a[i][ks] = *(const bf16x8*)(Ab + ((baseA + (4 + i) * 1024) ^ (ks * 32)));
    __builtin_amdgcn_s_setprio(1);
#pragma unroll
    for (int i = 0; i < 4; i++)
#pragma unroll
      for (int j = 0; j < 2; j++)
#pragma unroll
        for (int ks = 0; ks < 2; ks++)
          acc[4 + i][j] = __builtin_amdgcn_mfma_f32_16x16x32_bf16(a[i][ks], b0[j][ks], acc[4 + i][j], 0, 0, 0);
    __builtin_amdgcn_s_setprio(0);
    __builtin_amdgcn_s_barrier();          // all waves' A(c) reads done before STG_A overwrites
    // ---- P3: stage A(tt+2) into buf c; MFMA (i4-7, j2-3); counted vmcnt
    if (tt < 6) { STG_A(c, 0, tt + 2); STG_A(c, 1, tt + 2); }
    __builtin_amdgcn_s_setprio(1);
#pragma unroll
    for (int i = 0; i < 4; i++)
#pragma unroll
      for (int j = 0; j < 2; j++)
#pragma unroll
        for (int ks = 0; ks < 2; ks++)
          acc[4 + i][2 + j] = __builtin_amdgcn_mfma_f32_16x16x32_bf16(a[i][ks], b1[j][ks], acc[4 + i][2 + j], 0, 0, 0);
    __builtin_amdgcn_s_setprio(0);
    if (tt < 6) { asm volatile("s_waitcnt vmcnt(4)" ::: "memory"); }
    else        { asm volatile("s_waitcnt vmcnt(0)" ::: "memory"); }
    __builtin_amdgcn_s_barrier();
  }
#undef STG_A
#undef STG_B

  // ---------------- fused epilogue
  int third = n0 >> 9;
  int n0t = n0 & 511;
  int b = m0 >> 13;
  int tloc = m0 & 8191;

  if (third == 0) {
#pragma unroll
    for (int i = 0; i < 8; i++)
#pragma unroll
      for (int j = 0; j < 4; j++)
#pragma unroll
        for (int r = 0; r < 4; r++) acc[i][j][r] = __expf(acc[i][j][r] * 0.125f);
    // column sums -> S (softmax over tokens denominators)
#pragma unroll
    for (int j = 0; j < 4; j++) {
      float ps = 0.f;
#pragma unroll
      for (int i = 0; i < 8; i++)
#pragma unroll
        for (int r = 0; r < 4; r++) ps += acc[i][j][r];
      ps += __shfl_xor(ps, 16);
      ps += __shfl_xor(ps, 32);
      if (qd == 0) atomicAdd(S + b * 512 + n0t + wn * 64 + j * 16 + l15, ps);
    }
  } else if (third == 1) {
#pragma unroll
    for (int i = 0; i < 8; i++)
#pragma unroll
      for (int j = 0; j < 4; j++)
#pragma unroll
        for (int r = 0; r < 4; r++) acc[i][j][r] = __expf(acc[i][j][r]);
    int head = (n0t >> 6) + wn;
#pragma unroll
    for (int i = 0; i < 8; i++)
#pragma unroll
      for (int r = 0; r < 4; r++) {
        float rs = acc[i][0][r] + acc[i][1][r] + acc[i][2][r] + acc[i][3][r];
        rs += __shfl_xor(rs, 1);
        rs += __shfl_xor(rs, 2);
        rs += __shfl_xor(rs, 4);
        rs += __shfl_xor(rs, 8);
        if (l15 == 0)
          atomicAdd(Z + ((long)b * NH + head) * 8192 + tloc + wm * 128 + i * 16 + qd * 4 + r, rs);
      }
  }

  // stores via LDS restage (aliases staging buffers), two 128-row halves
  u16* Cs = smem;
  if (third == 0) {
    u16* dstb = qexp + ((long)b * 8192 + tloc) * 512 + n0t;
#pragma unroll
    for (int hh = 0; hh < 2; hh++) {
      if (hh) __syncthreads();
      if (wm == hh) {
#pragma unroll
        for (int i = 0; i < 8; i++)
#pragma unroll
          for (int r = 0; r < 4; r++)
#pragma unroll
            for (int j = 0; j < 4; j++)
              Cs[(i * 16 + qd * 4 + r) * 264 + wn * 64 + j * 16 + l15] = f2bf(acc[i][j][r]);
      }
      __syncthreads();
      u16* dst = dstb + (long)hh * 128 * 512;
#pragma unroll
      for (int z = 0; z < 8; z++) {
        int row = z * 16 + (tid >> 5);
        int off = (tid & 31) * 8;
        *(uint4*)(dst + (long)row * 512 + off) = *(const uint4*)(Cs + row * 264 + off);
      }
    }
  } else {
    u16* dstb = (third == 1 ? expkT : vT) + ((long)b * 512 + n0t) * 8192 + tloc;
#pragma unroll
    for (int hh = 0; hh < 2; hh++) {
      if (hh) __syncthreads();
      if (wm == hh) {
#pragma unroll
        for (int i = 0; i < 8; i++)
#pragma unroll
          for (int r = 0; r < 4; r++)
#pragma unroll
            for (int j = 0; j < 4; j++)
              Cs[(wn * 64 + j * 16 + l15) * 136 + i * 16 + qd * 4 + r] = f2bf(acc[i][j][r]);
      }
      __syncthreads();
#pragma unroll
      for (int z = 0; z < 8; z++) {
        int col = z * 32 + (tid >> 4);
        int moff = (tid & 15) * 8;
        *(uint4*)(dstb + (long)col * 8192 + hh * 128 + moff) = *(const uint4*)(Cs + col * 136 + moff);
      }
    }
  }
}

// ------------------------------------------------- Z -> 1/Z
__global__ __launch_bounds__(256) void zrecip(float* __restrict__ Z) {
  int i = blockIdx.x * 256 + threadIdx.x;
  Z[i] = 1.0f / Z[i];
}

// ------------------------------------------------- ctx[b,h,d,e] += sum_n expkT[d,n] * vT[e,n] * Zr[b,h,n]
__global__ __launch_bounds__(256) void ctx_kernel(const u16* __restrict__ expkT,
                                                  const u16* __restrict__ vT,
                                                  const float* __restrict__ Zr,
                                                  float* __restrict__ ctx) {
  __shared__ u16 As[64 * 128];
  __shared__ u16 Bs[64 * 128];
  int kc = blockIdx.x, hh = blockIdx.y, b = blockIdx.z;
  int t = threadIdx.x, w = t >> 6, l = t & 63, l15 = l & 15, qd = l >> 4;
  long nbase = (long)kc * 512;
  const u16* Abase = expkT + ((long)b * 512 + hh * 64) * 8192 + nbase;
  const u16* Bbase = vT   + ((long)b * 512 + hh * 64) * 8192 + nbase;
  const float* Zb = Zr + ((long)b * NH + hh) * 8192 + nbase;

  f32x4 zero = {0.f, 0.f, 0.f, 0.f};
  f32x4 acc[4] = {zero, zero, zero, zero};

  int brow = t >> 2;
  for (int s = 0; s < 4; s++) {
    long ko = (long)s * 128;
    __syncthreads();
#pragma unroll
    for (int si = 0; si < 4; si++) {
      int qq = si * 4 + w;
      int row = qq * 4 + (l >> 4);
      int gs = (l & 15) ^ (row & 15);
      GLOAD16(Abase + (long)row * 8192 + ko + gs * 8, As + qq * 512);
    }
    {
      const u16* src = Bbase + (long)brow * 8192 + ko;
#pragma unroll
      for (int cc = 0; cc < 4; cc++) {
        int c = (t & 3) * 4 + cc;
        u16x8 v8 = *(const u16x8*)(src + c * 8);
        float4 z0 = *(const float4*)(Zb + ko + c * 8);
        float4 z1 = *(const float4*)(Zb + ko + c * 8 + 4);
        u16x8 o;
        o[0] = f2bf(bf2f(v8[0]) * z0.x); o[1] = f2bf(bf2f(v8[1]) * z0.y);
        o[2] = f2bf(bf2f(v8[2]) * z0.z); o[3] = f2bf(bf2f(v8[3]) * z0.w);
        o[4] = f2bf(bf2f(v8[4]) * z1.x); o[5] = f2bf(bf2f(v8[5]) * z1.y);
        o[6] = f2bf(bf2f(v8[6]) * z1.z); o[7] = f2bf(bf2f(v8[7]) * z1.w);
        *(u16x8*)(Bs + brow * 128 + ((c ^ (brow & 15)) * 8)) = o;
      }
    }
    __syncthreads();
#pragma unroll
    for (int kk = 0; kk < 4; kk++) {
      int ar = w * 16 + l15;
      bf16x8 af = *(const bf16x8*)(As + ar * 128 + (((kk * 4 + qd) ^ (ar & 15)) * 8));
#pragma unroll
      for (int j = 0; j < 4; j++) {
        int br = j * 16 + l15;
        bf16x8 bf8 = *(const bf16x8*)(Bs + br * 128 + (((kk * 4 + qd) ^ (br & 15)) * 8));
        acc[j] = __builtin_amdgcn_mfma_f32_16x16x32_bf16(af, bf8, acc[j], 0, 0, 0);
      }
    }
  }
  float* cp = ctx + ((long)(b * NH + hh)) * DH * DH;
#pragma unroll
  for (int j = 0; j < 4; j++)
#pragma unroll
    for (int r = 0; r < 4; r++)
      atomicAdd(cp + (w * 16 + qd * 4 + r) * 64 + j * 16 + l15, acc[j][r]);
}

// ------------------------------------------------- mprime
__global__ __launch_bounds__(256) void mprime(const float* __restrict__ ctx,
                                              const float* __restrict__ wout,
                                              const float* __restrict__ S,
                                              u16* __restrict__ Mt) {
  __shared__ float ws[64 * 65];
  __shared__ float cs[64 * 65];
  int dt = blockIdx.x, hh = blockIdx.y, b = blockIdx.z;
  int t = threadIdx.x;
  {
    int e = t >> 2;
#pragma unroll
    for (int ii = 0; ii < 4; ii++) {
      int col = (t & 3) * 16 + ii * 4;
      float4 v = *(const float4*)(wout + (long)(hh * 64 + e) * 512 + dt * 64 + col);
      ws[e * 65 + col] = v.x; ws[e * 65 + col + 1] = v.y;
      ws[e * 65 + col + 2] = v.z; ws[e * 65 + col + 3] = v.w;
      float4 c = *(const float4*)(ctx + ((long)(b * NH + hh)) * 4096 + (long)e * 64 + col);
      cs[e * 65 + col] = c.x; cs[e * 65 + col + 1] = c.y;
      cs[e * 65 + col + 2] = c.z; cs[e * 65 + col + 3] = c.w;
    }
  }
  __syncthreads();
  int dol = t & 63, dg = t >> 6;
#pragma unroll
  for (int dd = 0; dd < 16; dd++) {
    int d = dg * 16 + dd;
    float v = 0.f;
#pragma unroll 8
    for (int e = 0; e < 64; e++) v += cs[d * 65 + e] * ws[e * 65 + dol];
    float sv = S[b * 512 + hh * 64 + d];
    Mt[(long)b * 262144 + (long)(dt * 64 + dol) * 512 + hh * 64 + d] = f2bf(v / sv);
  }
}

// ------------------------------------------------- GEMM2 (TN), fp32 out + bias
__global__ __launch_bounds__(256) void gemm_tn_f(const u16* __restrict__ A,
                                                 const u16* __restrict__ B,
                                                 float* __restrict__ C,
                                                 const float* __restrict__ bias,
                                                 int K, int ldc,
                                                 long sA, long sB, long sC) {
  __shared__ alignas(16) u16 smem[17408];
  float* Cf = (float*)smem;

  int bid = (blockIdx.z * gridDim.y + blockIdx.y) * gridDim.x + blockIdx.x;
  int wid = (bid & 7) * 128 + (bid >> 3);
  int mx = wid & 3;
  int ny = (wid >> 2) & 63;
  long bz = wid >> 8;
  A += bz * sA; B += bz * sB; C += bz * sC;
  int m0 = mx * 128, n0 = ny * 128;

  int tid = threadIdx.x, wave = tid >> 6, lane = tid & 63;
  int l15 = lane & 15, qd = lane >> 4;

  int ra0 = tid >> 2,          qa0 = (tid & 3) ^ ((ra0 >> 1) & 3);
  int ra1 = (tid + 256) >> 2,  qa1 = (tid & 3) ^ ((ra1 >> 1) & 3);
  const u16* gA0 = A + (long)(m0 + ra0) * K + qa0 * 8;
  const u16* gA1 = A + (long)(m0 + ra1) * K + qa1 * 8;
  const u16* gB0 = B + (long)(n0 + ra0) * K + qa0 * 8;
  const u16* gB1 = B + (long)(n0 + ra1) * K + qa1 * 8;

  int wm = wave & 1, wn = wave >> 1;
  int aoff[4], boff[4];
#pragma unroll
  for (int i = 0; i < 4; i++) {
    int r = wm * 64 + i * 16 + l15;
    aoff[i] = r * 32 + ((qd ^ ((r >> 1) & 3)) * 8);
    int rb = wn * 64 + i * 16 + l15;
    boff[i] = rb * 32 + ((qd ^ ((rb >> 1) & 3)) * 8);
  }

  f32x4 zero = {0.f, 0.f, 0.f, 0.f};
  f32x4 acc[4][4];
#pragma unroll
  for (int i = 0; i < 4; i++)
#pragma unroll
    for (int j = 0; j < 4; j++) acc[i][j] = zero;

#define STAGE2(buf, kk) { \
    u16* dA = smem + (buf) * 8192 + wave * 512; \
    u16* dB = smem + (buf) * 8192 + 4096 + wave * 512; \
    GLOAD16(gA0 + (kk), dA); GLOAD16(gA1 + (kk), dA + 2048); \
    GLOAD16(gB0 + (kk), dB); GLOAD16(gB1 + (kk), dB + 2048); }

  STAGE2(0, 0);
  asm volatile("s_waitcnt vmcnt(0)" ::: "memory");
  __builtin_amdgcn_s_barrier();

#pragma unroll
  for (int it = 0; it < 15; it++) {
    const int cur = it & 1, nxt = cur ^ 1;
    STAGE2(nxt, (it + 1) * 32);
    const u16* Ac = smem + cur * 8192;
    const u16* Bc = smem + cur * 8192 + 4096;
    bf16x8 af[4], bf[4];
#pragma unroll
    for (int q = 0; q < 4; q++) {
      af[q] = *(const bf16x8*)(Ac + aoff[q]);
      bf[q] = *(const bf16x8*)(Bc + boff[q]);
    }
#pragma unroll
    for (int i = 0; i < 4; i++)
#pragma unroll
      for (int j = 0; j < 4; j++)
        acc[i][j] = __builtin_amdgcn_mfma_f32_16x16x32_bf16(af[i], bf[j], acc[i][j], 0, 0, 0);
    asm volatile("s_waitcnt vmcnt(0) lgkmcnt(0)" ::: "memory");
    __builtin_amdgcn_s_barrier();
  }
  {
    const u16* Ac = smem + 8192;
    const u16* Bc = smem + 8192 + 4096;
    bf16x8 af[4], bf[4];
#pragma unroll
    for (int q = 0; q < 4; q++) {
      af[q] = *(const bf16x8*)(Ac + aoff[q]);
      bf[q] = *(const bf16x8*)(Bc + boff[q]);
    }
#pragma unroll
    for (int i = 0; i < 4; i++)
#pragma unroll
      for (int j = 0; j < 4; j++)
        acc[i][j] = __builtin_amdgcn_mfma_f32_16x16x32_bf16(af[i], bf[j], acc[i][j], 0, 0, 0);
  }
  asm volatile("s_waitcnt lgkmcnt(0)" ::: "memory");
  __builtin_amdgcn_s_barrier();
#undef STAGE2

#pragma unroll
  for (int half = 0; half < 2; half++) {
    __syncthreads();
    if (wm == half) {
#pragma unroll
      for (int i = 0; i < 4; i++)
#pragma unroll
        for (int r = 0; r < 4; r++) {
          int rrl = i * 16 + qd * 4 + r;
          float bv = bias[m0 + half * 64 + rrl];
#pragma unroll
          for (int j = 0; j < 4; j++)
            Cf[rrl * 133 + wn * 64 + j * 16 + l15] = acc[i][j][r] + bv;
        }
    }
    __syncthreads();
#pragma unroll
    for (int z = 0; z < 2; z++) {
      int rrl = z * 32 + (tid >> 3);
      int seg = tid & 7;
      float* dp = C + (long)(m0 + half * 64 + rrl) * ldc + n0;
      const float* src = Cf + rrl * 133;
#pragma unroll
      for (int p = 0; p < 4; p++)
        *(float4*)(dp + p * 32 + seg * 4) = *(const float4*)(src + p * 32 + seg * 4);
    }
  }
}

// ------------------------------------------------- launch
extern "C" void kernel_launch(void* const* d_in, const int* in_sizes, int n_in,
                              void* d_out, int out_size, void* d_ws, size_t ws_size,
                              hipStream_t stream) {
  const float* x    = (const float*)d_in[0];
  const float* lnw  = (const float*)d_in[1];
  const float* lnb  = (const float*)d_in[2];
  const float* wqkv = (const float*)d_in[3];
  const float* wout = (const float*)d_in[4];
  const float* bout = (const float*)d_in[5];
  float* out = (float*)d_out;
  char* ws = (char*)d_ws;

  u16*  h     = (u16*)(ws + 0L);              // 32 MB (b,n,d) bf16
  u16*  qexp  = (u16*)(ws + 33554432L);       // 32 MB (b,n,512) bf16
  u16*  expkT = (u16*)(ws + 67108864L);       // 32 MB (b,512,n) bf16
  u16*  vT    = (u16*)(ws + 100663296L);      // 32 MB (b,512,n) bf16
  u16*  wqkvT = (u16*)(ws + 134217728L);      // 1.5 MB
  u16*  Mt    = (u16*)(ws + 134217728L);      // 2 MB, reuses wqkvT region (after gemm1)
  float* S    = (float*)(ws + 136314880L);    // 8 KB
  float* ctx  = (float*)(ws + 0L);            // 512 KB, aliases h (dead after gemm1)
  float* Z    = (float*)d_out;                // 1 MB, dead before gemm_tn_f writes out

  hipMemsetAsync(S, 0, 4 * 512 * 4, stream);
  hipMemsetAsync(Z, 0, (long)B_ * NH * 8192 * 4, stream);

  transpose_f2b<<<dim3(24, 8), 256, 0, stream>>>(wqkv, wqkvT, 512, 1536);

  ln_kernel<<<dim3(256, 4), 256, 0, stream>>>(x, lnw, lnb, h);

  gemm1<<<dim3(6, 128), 512, 0, stream>>>(h, wqkvT, qexp, expkT, vT, S, Z);

  zrecip<<<dim3(1024), 256, 0, stream>>>(Z);

  hipMemsetAsync(ctx, 0, 4 * 8 * 64 * 64 * 4, stream);

  ctx_kernel<<<dim3(16, 8, 4), 256, 0, stream>>>(expkT, vT, Z, ctx);

  mprime<<<dim3(8, 8, 4), 256, 0, stream>>>(ctx, wout, S, Mt);

  gemm_tn_f<<<dim3(4, 64, 4), 256, 0, stream>>>(Mt, qexp, out, bout, 512, 8192,
                                                262144L, (long)8192 * 512, (long)512 * 8192);
}

// Round 6
// 282.521 us; speedup vs baseline: 1.1552x; 1.1014x over previous
//
#include <hip/hip_runtime.h>

#define B_   4
#define N_   8192
#define D_   512
#define NH   8
#define DH   64
#define HID  512

typedef unsigned short u16;
typedef __attribute__((ext_vector_type(8))) short  bf16x8;
typedef __attribute__((ext_vector_type(8))) unsigned short u16x8;
typedef __attribute__((ext_vector_type(4))) float  f32x4;

__device__ __forceinline__ float bf2f(u16 u) {
  unsigned int i = ((unsigned int)u) << 16;
  return __builtin_bit_cast(float, i);
}
__device__ __forceinline__ u16 f2bf(float f) {
  unsigned int i = __builtin_bit_cast(unsigned int, f);
  i += 0x7fff + ((i >> 16) & 1);
  return (u16)(i >> 16);
}

#define GLOAD16(g, l) \
  __builtin_amdgcn_global_load_lds((const __attribute__((address_space(1))) void*)(g), \
                                   (__attribute__((address_space(3))) void*)(l), 16, 0, 0)

// ------------------------------------------------- tiled transpose fp32 -> bf16
// Also zeroes S (first 8 blocks) so the separate memset dispatch is dropped.
__global__ __launch_bounds__(256) void transpose_f2b(const float* __restrict__ in,
                                                     u16* __restrict__ out,
                                                     int rows, int cols,
                                                     float* __restrict__ S0) {
  __shared__ u16 tile[64][65];
  int c0 = blockIdx.x * 64, r0 = blockIdx.y * 64;
  int t = threadIdx.x;
  if (blockIdx.y == 0 && blockIdx.x < 8) S0[blockIdx.x * 256 + t] = 0.f;
  int rl = t >> 6, cl = t & 63;
#pragma unroll
  for (int i = 0; i < 16; i++) {
    int r = i * 4 + rl;
    tile[r][cl] = f2bf(in[(long)(r0 + r) * cols + c0 + cl]);
  }
  __syncthreads();
  int c4 = t >> 6, rr = t & 63;
#pragma unroll
  for (int i = 0; i < 16; i++) {
    int c = i * 4 + c4;
    out[(long)(c0 + c) * rows + r0 + rr] = tile[rr][c];
  }
}

// ------------------------------------------------- layernorm, single HBM pass
__global__ __launch_bounds__(256) void ln_kernel(const float* __restrict__ x,
                                                 const float* __restrict__ lw,
                                                 const float* __restrict__ lb,
                                                 u16* __restrict__ h) {
  __shared__ u16 xs[32 * 520];
  __shared__ float red[2][8][32];
  __shared__ float murs[2][32];
  __shared__ float lws[512], lbs[512];
  int b = blockIdx.y, n0 = blockIdx.x * 32;
  int t = threadIdx.x;
  lws[t] = lw[t]; lws[t + 256] = lw[t + 256];
  lbs[t] = lb[t]; lbs[t + 256] = lb[t + 256];
  int tok = t & 31, dp = t >> 5;
  const float* xp = x + (long)b * D_ * N_ + n0 + tok;
  float s = 0.f, s2 = 0.f;
#pragma unroll 8
  for (int i = 0; i < 64; i++) {
    int d = dp * 64 + i;
    float v = xp[(long)d * N_];
    s += v; s2 += v * v;
    xs[tok * 520 + d] = f2bf(v);
  }
  red[0][dp][tok] = s; red[1][dp][tok] = s2;
  __syncthreads();
  if (t < 32) {
    float S1 = 0.f, S2 = 0.f;
#pragma unroll
    for (int i = 0; i < 8; i++) { S1 += red[0][i][t]; S2 += red[1][i][t]; }
    float mu = S1 * (1.0f / 512.0f);
    float var = S2 * (1.0f / 512.0f) - mu * mu;
    murs[0][t] = mu; murs[1][t] = rsqrtf(var + 1e-5f);
  }
  __syncthreads();
  int row = t >> 3, seg = t & 7;
  float mu = murs[0][row], rs = murs[1][row];
  u16* hp = h + ((long)b * N_ + n0 + row) * D_;
  const u16* xr = xs + row * 520;
#pragma unroll
  for (int c = 0; c < 8; c++) {
    int d0 = c * 64 + seg * 8;
    u16x8 in8 = *(const u16x8*)(xr + d0);
    u16x8 o;
#pragma unroll
    for (int i = 0; i < 8; i++) {
      int d = d0 + i;
      o[i] = f2bf((bf2f(in8[i]) - mu) * rs * lws[d] + lbs[d]);
    }
    *(u16x8*)(hp + d0) = o;
  }
}

// ------------------------------------------------- GEMM1: h @ wqkv with fused softmax prep
// R2-proven 2-phase double-buffered K-loop, LDS dbuf aliased with epilogue Cs,
// XCD-chunked swizzle. Z written directly as reciprocal (single-writer proof:
// each Z[b,h,token] has exactly one contributing (block,lane) — no atomic, no
// memset, no zrecip pass needed).
// NOTE (R3-R5 lesson): the 256²/512-thread variant caps unified regs at 256/wave
// (acc=128 AGPR + 128 arch) and the unrolled K-loop spills ~5 regs/iter ->
// ~108MB/dispatch scratch traffic, 122µs vs this kernel's 82µs. Do not retry
// without #pragma unroll 1 + verified liveness.
__global__ __launch_bounds__(256) void gemm1(const u16* __restrict__ A,
                                             const u16* __restrict__ B,
                                             u16* __restrict__ qexp,
                                             u16* __restrict__ expkT,
                                             u16* __restrict__ vT,
                                             float* __restrict__ S,
                                             float* __restrict__ Z) {
  const int K = 512;
  // [buf0: As 4096 u16 | Bs 4096][buf1: As | Bs] = 32768B; epilogue Cs = 17408 u16 = 34816B
  __shared__ alignas(16) u16 smem[17408];

  // XCD-chunked swizzle: nwg = 3072, 384 contiguous work-ids per XCD.
  int bid = blockIdx.y * 12 + blockIdx.x;
  int wid = (bid & 7) * 384 + (bid >> 3);
  int bx = wid % 12, by = wid / 12;
  int m0 = by * 128, n0 = bx * 128;

  int tid = threadIdx.x, wave = tid >> 6, lane = tid & 63;
  int l15 = lane & 15, qd = lane >> 4;

  int ra0 = tid >> 2,          qa0 = (tid & 3) ^ ((ra0 >> 1) & 3);
  int ra1 = (tid + 256) >> 2,  qa1 = (tid & 3) ^ ((ra1 >> 1) & 3);
  const u16* gA0 = A + (long)(m0 + ra0) * K + qa0 * 8;
  const u16* gA1 = A + (long)(m0 + ra1) * K + qa1 * 8;
  const u16* gB0 = B + (long)(n0 + ra0) * K + qa0 * 8;
  const u16* gB1 = B + (long)(n0 + ra1) * K + qa1 * 8;

  int wm = wave & 1, wn = wave >> 1;
  int aoff[4], boff[4];
#pragma unroll
  for (int i = 0; i < 4; i++) {
    int r = wm * 64 + i * 16 + l15;
    aoff[i] = r * 32 + ((qd ^ ((r >> 1) & 3)) * 8);
    int rb = wn * 64 + i * 16 + l15;
    boff[i] = rb * 32 + ((qd ^ ((rb >> 1) & 3)) * 8);
  }

  f32x4 zero = {0.f, 0.f, 0.f, 0.f};
  f32x4 acc[4][4];
#pragma unroll
  for (int i = 0; i < 4; i++)
#pragma unroll
    for (int j = 0; j < 4; j++) acc[i][j] = zero;

#define STAGE1(buf, kk) { \
    u16* dA = smem + (buf) * 8192 + wave * 512; \
    u16* dB = smem + (buf) * 8192 + 4096 + wave * 512; \
    GLOAD16(gA0 + (kk), dA); GLOAD16(gA1 + (kk), dA + 2048); \
    GLOAD16(gB0 + (kk), dB); GLOAD16(gB1 + (kk), dB + 2048); }

  // prologue: stage tile 0
  STAGE1(0, 0);
  asm volatile("s_waitcnt vmcnt(0)" ::: "memory");
  __builtin_amdgcn_s_barrier();

#pragma unroll
  for (int it = 0; it < 15; it++) {
    const int cur = it & 1, nxt = cur ^ 1;
    STAGE1(nxt, (it + 1) * 32);            // issue next tile; latency hides under compute
    const u16* Ac = smem + cur * 8192;
    const u16* Bc = smem + cur * 8192 + 4096;
    bf16x8 af[4], bf[4];
#pragma unroll
    for (int q = 0; q < 4; q++) {
      af[q] = *(const bf16x8*)(Ac + aoff[q]);
      bf[q] = *(const bf16x8*)(Bc + boff[q]);
    }
#pragma unroll
    for (int i = 0; i < 4; i++)
#pragma unroll
      for (int j = 0; j < 4; j++)
        acc[i][j] = __builtin_amdgcn_mfma_f32_16x16x32_bf16(af[i], bf[j], acc[i][j], 0, 0, 0);
    asm volatile("s_waitcnt vmcnt(0) lgkmcnt(0)" ::: "memory");
    __builtin_amdgcn_s_barrier();          // next tile resident; all readers of cur done
  }
  { // last tile (cur = 1), no stage
    const u16* Ac = smem + 8192;
    const u16* Bc = smem + 8192 + 4096;
    bf16x8 af[4], bf[4];
#pragma unroll
    for (int q = 0; q < 4; q++) {
      af[q] = *(const bf16x8*)(Ac + aoff[q]);
      bf[q] = *(const bf16x8*)(Bc + boff[q]);
    }
#pragma unroll
    for (int i = 0; i < 4; i++)
#pragma unroll
      for (int j = 0; j < 4; j++)
        acc[i][j] = __builtin_amdgcn_mfma_f32_16x16x32_bf16(af[i], bf[j], acc[i][j], 0, 0, 0);
  }
  asm volatile("s_waitcnt lgkmcnt(0)" ::: "memory");
  __builtin_amdgcn_s_barrier();            // safe to overwrite smem with Cs
#undef STAGE1

  u16* Cs = smem;                          // epilogue staging aliases the K-loop buffers

  int third = n0 >> 9;
  int n0t = n0 & 511;
  int b = m0 >> 13;
  int tloc = m0 & 8191;

  if (third == 0) {
#pragma unroll
    for (int i = 0; i < 4; i++)
#pragma unroll
      for (int j = 0; j < 4; j++)
#pragma unroll
        for (int r = 0; r < 4; r++) acc[i][j][r] = __expf(acc[i][j][r] * 0.125f);
#pragma unroll
    for (int j = 0; j < 4; j++) {
      float ps = 0.f;
#pragma unroll
      for (int i = 0; i < 4; i++)
#pragma unroll
        for (int r = 0; r < 4; r++) ps += acc[i][j][r];
      ps += __shfl_xor(ps, 16);
      ps += __shfl_xor(ps, 32);
      if (qd == 0) atomicAdd(S + b * 512 + n0t + wn * 64 + j * 16 + l15, ps);
    }
  } else if (third == 1) {
#pragma unroll
    for (int i = 0; i < 4; i++)
#pragma unroll
      for (int j = 0; j < 4; j++)
#pragma unroll
        for (int r = 0; r < 4; r++) acc[i][j][r] = __expf(acc[i][j][r]);
    int head = (n0t >> 6) + wn;
#pragma unroll
    for (int i = 0; i < 4; i++)
#pragma unroll
      for (int r = 0; r < 4; r++) {
        float rs = acc[i][0][r] + acc[i][1][r] + acc[i][2][r] + acc[i][3][r];
        rs += __shfl_xor(rs, 1);
        rs += __shfl_xor(rs, 2);
        rs += __shfl_xor(rs, 4);
        rs += __shfl_xor(rs, 8);
        // single-writer per Z element: direct reciprocal store (no atomic/memset/zrecip)
        if (l15 == 0)
          Z[((long)b * NH + head) * 8192 + tloc + wm * 64 + i * 16 + qd * 4 + r] = 1.0f / rs;
      }
  }

  if (third == 0) {
#pragma unroll
    for (int i = 0; i < 4; i++)
#pragma unroll
      for (int r = 0; r < 4; r++)
#pragma unroll
        for (int j = 0; j < 4; j++)
          Cs[(wm * 64 + i * 16 + qd * 4 + r) * 136 + wn * 64 + j * 16 + l15] =
              f2bf(acc[i][j][r]);
  } else {
#pragma unroll
    for (int i = 0; i < 4; i++)
#pragma unroll
      for (int r = 0; r < 4; r++)
#pragma unroll
        for (int j = 0; j < 4; j++)
          Cs[(wn * 64 + j * 16 + l15) * 136 + wm * 64 + i * 16 + qd * 4 + r] =
              f2bf(acc[i][j][r]);
  }
  __syncthreads();

  u16* dst; long ldg;
  if (third == 0)      { dst = qexp  + ((long)b * N_ + tloc) * 512 + n0t;  ldg = 512; }
  else if (third == 1) { dst = expkT + ((long)b * 512 + n0t) * 8192 + tloc; ldg = 8192; }
  else                 { dst = vT    + ((long)b * 512 + n0t) * 8192 + tloc; ldg = 8192; }

  // full-line stores: 8 lanes cover 128B contiguous of one row per instruction
  int seg = lane & 7;
#pragma unroll
  for (int outer = 0; outer < 2; outer++)
#pragma unroll
    for (int rr = 0; rr < 2; rr++) {
      int row = outer * 64 + wave * 16 + rr * 8 + (lane >> 3);
      const u16* src = Cs + row * 136;
      u16* dp = dst + (long)row * ldg;
#pragma unroll
      for (int p = 0; p < 2; p++)
        *(uint4*)(dp + p * 64 + seg * 8) = *(const uint4*)(src + p * 64 + seg * 8);
    }
}

// ------------------------------------------------- ctx[b,h,d,e] += sum_n expkT[d,n] * vT[e,n] * Zr[b,h,n]
// Zr already holds reciprocals (written by gemm1).
__global__ __launch_bounds__(256) void ctx_kernel(const u16* __restrict__ expkT,
                                                  const u16* __restrict__ vT,
                                                  const float* __restrict__ Zr,
                                                  float* __restrict__ ctx) {
  __shared__ u16 As[64 * 128];
  __shared__ u16 Bs[64 * 128];
  int kc = blockIdx.x, hh = blockIdx.y, b = blockIdx.z;
  int t = threadIdx.x, w = t >> 6, l = t & 63, l15 = l & 15, qd = l >> 4;
  long nbase = (long)kc * 512;
  const u16* Abase = expkT + ((long)b * 512 + hh * 64) * 8192 + nbase;
  const u16* Bbase = vT   + ((long)b * 512 + hh * 64) * 8192 + nbase;
  const float* Zb = Zr + ((long)b * NH + hh) * 8192 + nbase;

  f32x4 zero = {0.f, 0.f, 0.f, 0.f};
  f32x4 acc[4] = {zero, zero, zero, zero};

  int brow = t >> 2;
  for (int s = 0; s < 4; s++) {
    long ko = (long)s * 128;
    __syncthreads();
#pragma unroll
    for (int si = 0; si < 4; si++) {
      int qq = si * 4 + w;
      int row = qq * 4 + (l >> 4);
      int gs = (l & 15) ^ (row & 15);
      GLOAD16(Abase + (long)row * 8192 + ko + gs * 8, As + qq * 512);
    }
    {
      const u16* src = Bbase + (long)brow * 8192 + ko;
#pragma unroll
      for (int cc = 0; cc < 4; cc++) {
        int c = (t & 3) * 4 + cc;
        u16x8 v8 = *(const u16x8*)(src + c * 8);
        float4 z0 = *(const float4*)(Zb + ko + c * 8);
        float4 z1 = *(const float4*)(Zb + ko + c * 8 + 4);
        u16x8 o;
        o[0] = f2bf(bf2f(v8[0]) * z0.x); o[1] = f2bf(bf2f(v8[1]) * z0.y);
        o[2] = f2bf(bf2f(v8[2]) * z0.z); o[3] = f2bf(bf2f(v8[3]) * z0.w);
        o[4] = f2bf(bf2f(v8[4]) * z1.x); o[5] = f2bf(bf2f(v8[5]) * z1.y);
        o[6] = f2bf(bf2f(v8[6]) * z1.z); o[7] = f2bf(bf2f(v8[7]) * z1.w);
        *(u16x8*)(Bs + brow * 128 + ((c ^ (brow & 15)) * 8)) = o;
      }
    }
    __syncthreads();
#pragma unroll
    for (int kk = 0; kk < 4; kk++) {
      int ar = w * 16 + l15;
      bf16x8 af = *(const bf16x8*)(As + ar * 128 + (((kk * 4 + qd) ^ (ar & 15)) * 8));
#pragma unroll
      for (int j = 0; j < 4; j++) {
        int br = j * 16 + l15;
        bf16x8 bf8 = *(const bf16x8*)(Bs + br * 128 + (((kk * 4 + qd) ^ (br & 15)) * 8));
        acc[j] = __builtin_amdgcn_mfma_f32_16x16x32_bf16(af, bf8, acc[j], 0, 0, 0);
      }
    }
  }
  float* cp = ctx + ((long)(b * NH + hh)) * DH * DH;
#pragma unroll
  for (int j = 0; j < 4; j++)
#pragma unroll
    for (int r = 0; r < 4; r++)
      atomicAdd(cp + (w * 16 + qd * 4 + r) * 64 + j * 16 + l15, acc[j][r]);
}

// ------------------------------------------------- mprime
__global__ __launch_bounds__(256) void mprime(const float* __restrict__ ctx,
                                              const float* __restrict__ wout,
                                              const float* __restrict__ S,
                                              u16* __restrict__ Mt) {
  __shared__ float ws[64 * 65];
  __shared__ float cs[64 * 65];
  int dt = blockIdx.x, hh = blockIdx.y, b = blockIdx.z;
  int t = threadIdx.x;
  {
    int e = t >> 2;
#pragma unroll
    for (int ii = 0; ii < 4; ii++) {
      int col = (t & 3) * 16 + ii * 4;
      float4 v = *(const float4*)(wout + (long)(hh * 64 + e) * 512 + dt * 64 + col);
      ws[e * 65 + col] = v.x; ws[e * 65 + col + 1] = v.y;
      ws[e * 65 + col + 2] = v.z; ws[e * 65 + col + 3] = v.w;
      float4 c = *(const float4*)(ctx + ((long)(b * NH + hh)) * 4096 + (long)e * 64 + col);
      cs[e * 65 + col] = c.x; cs[e * 65 + col + 1] = c.y;
      cs[e * 65 + col + 2] = c.z; cs[e * 65 + col + 3] = c.w;
    }
  }
  __syncthreads();
  int dol = t & 63, dg = t >> 6;
#pragma unroll
  for (int dd = 0; dd < 16; dd++) {
    int d = dg * 16 + dd;
    float v = 0.f;
#pragma unroll 8
    for (int e = 0; e < 64; e++) v += cs[d * 65 + e] * ws[e * 65 + dol];
    float sv = S[b * 512 + hh * 64 + d];
    Mt[(long)b * 262144 + (long)(dt * 64 + dol) * 512 + hh * 64 + d] = f2bf(v / sv);
  }
}

// ------------------------------------------------- GEMM2 (TN), fp32 out + bias
// 2-phase dbuf K-loop + Cf aliasing + XCD swizzle. grid (4 M, 64 N, 4 b)
__global__ __launch_bounds__(256) void gemm_tn_f(const u16* __restrict__ A,
                                                 const u16* __restrict__ B,
                                                 float* __restrict__ C,
                                                 const float* __restrict__ bias,
                                                 int K, int ldc,
                                                 long sA, long sB, long sC) {
  // dbuf: 32768B; epilogue Cf = 64*133 f32 = 34048B; union = 34816B
  __shared__ alignas(16) u16 smem[17408];
  float* Cf = (float*)smem;

  // XCD-chunked swizzle: nwg = 1024, 128 contiguous work-ids per XCD.
  int bid = (blockIdx.z * gridDim.y + blockIdx.y) * gridDim.x + blockIdx.x;
  int wid = (bid & 7) * 128 + (bid >> 3);
  int mx = wid & 3;
  int ny = (wid >> 2) & 63;
  long bz = wid >> 8;
  A += bz * sA; B += bz * sB; C += bz * sC;
  int m0 = mx * 128, n0 = ny * 128;

  int tid = threadIdx.x, wave = tid >> 6, lane = tid & 63;
  int l15 = lane & 15, qd = lane >> 4;

  int ra0 = tid >> 2,          qa0 = (tid & 3) ^ ((ra0 >> 1) & 3);
  int ra1 = (tid + 256) >> 2,  qa1 = (tid & 3) ^ ((ra1 >> 1) & 3);
  const u16* gA0 = A + (long)(m0 + ra0) * K + qa0 * 8;
  const u16* gA1 = A + (long)(m0 + ra1) * K + qa1 * 8;
  const u16* gB0 = B + (long)(n0 + ra0) * K + qa0 * 8;
  const u16* gB1 = B + (long)(n0 + ra1) * K + qa1 * 8;

  int wm = wave & 1, wn = wave >> 1;
  int aoff[4], boff[4];
#pragma unroll
  for (int i = 0; i < 4; i++) {
    int r = wm * 64 + i * 16 + l15;
    aoff[i] = r * 32 + ((qd ^ ((r >> 1) & 3)) * 8);
    int rb = wn * 64 + i * 16 + l15;
    boff[i] = rb * 32 + ((qd ^ ((rb >> 1) & 3)) * 8);
  }

  f32x4 zero = {0.f, 0.f, 0.f, 0.f};
  f32x4 acc[4][4];
#pragma unroll
  for (int i = 0; i < 4; i++)
#pragma unroll
    for (int j = 0; j < 4; j++) acc[i][j] = zero;

#define STAGE2(buf, kk) { \
    u16* dA = smem + (buf) * 8192 + wave * 512; \
    u16* dB = smem + (buf) * 8192 + 4096 + wave * 512; \
    GLOAD16(gA0 + (kk), dA); GLOAD16(gA1 + (kk), dA + 2048); \
    GLOAD16(gB0 + (kk), dB); GLOAD16(gB1 + (kk), dB + 2048); }

  STAGE2(0, 0);
  asm volatile("s_waitcnt vmcnt(0)" ::: "memory");
  __builtin_amdgcn_s_barrier();

#pragma unroll
  for (int it = 0; it < 15; it++) {
    const int cur = it & 1, nxt = cur ^ 1;
    STAGE2(nxt, (it + 1) * 32);
    const u16* Ac = smem + cur * 8192;
    const u16* Bc = smem + cur * 8192 + 4096;
    bf16x8 af[4], bf[4];
#pragma unroll
    for (int q = 0; q < 4; q++) {
      af[q] = *(const bf16x8*)(Ac + aoff[q]);
      bf[q] = *(const bf16x8*)(Bc + boff[q]);
    }
#pragma unroll
    for (int i = 0; i < 4; i++)
#pragma unroll
      for (int j = 0; j < 4; j++)
        acc[i][j] = __builtin_amdgcn_mfma_f32_16x16x32_bf16(af[i], bf[j], acc[i][j], 0, 0, 0);
    asm volatile("s_waitcnt vmcnt(0) lgkmcnt(0)" ::: "memory");
    __builtin_amdgcn_s_barrier();
  }
  {
    const u16* Ac = smem + 8192;
    const u16* Bc = smem + 8192 + 4096;
    bf16x8 af[4], bf[4];
#pragma unroll
    for (int q = 0; q < 4; q++) {
      af[q] = *(const bf16x8*)(Ac + aoff[q]);
      bf[q] = *(const bf16x8*)(Bc + boff[q]);
    }
#pragma unroll
    for (int i = 0; i < 4; i++)
#pragma unroll
      for (int j = 0; j < 4; j++)
        acc[i][j] = __builtin_amdgcn_mfma_f32_16x16x32_bf16(af[i], bf[j], acc[i][j], 0, 0, 0);
  }
  asm volatile("s_waitcnt lgkmcnt(0)" ::: "memory");
  __builtin_amdgcn_s_barrier();
#undef STAGE2

#pragma unroll
  for (int half = 0; half < 2; half++) {
    __syncthreads();
    if (wm == half) {
#pragma unroll
      for (int i = 0; i < 4; i++)
#pragma unroll
        for (int r = 0; r < 4; r++) {
          int rrl = i * 16 + qd * 4 + r;
          float bv = bias[m0 + half * 64 + rrl];
#pragma unroll
          for (int j = 0; j < 4; j++)
            Cf[rrl * 133 + wn * 64 + j * 16 + l15] = acc[i][j][r] + bv;
        }
    }
    __syncthreads();
#pragma unroll
    for (int z = 0; z < 2; z++) {
      int rrl = z * 32 + (tid >> 3);
      int seg = tid & 7;
      float* dp = C + (long)(m0 + half * 64 + rrl) * ldc + n0;
      const float* src = Cf + rrl * 133;
#pragma unroll
      for (int p = 0; p < 4; p++)
        *(float4*)(dp + p * 32 + seg * 4) = *(const float4*)(src + p * 32 + seg * 4);
    }
  }
}

// ------------------------------------------------- launch
extern "C" void kernel_launch(void* const* d_in, const int* in_sizes, int n_in,
                              void* d_out, int out_size, void* d_ws, size_t ws_size,
                              hipStream_t stream) {
  const float* x    = (const float*)d_in[0];
  const float* lnw  = (const float*)d_in[1];
  const float* lnb  = (const float*)d_in[2];
  const float* wqkv = (const float*)d_in[3];
  const float* wout = (const float*)d_in[4];
  const float* bout = (const float*)d_in[5];
  float* out = (float*)d_out;
  char* ws = (char*)d_ws;

  u16*  h     = (u16*)(ws + 0L);              // 32 MB (b,n,d) bf16
  u16*  qexp  = (u16*)(ws + 33554432L);       // 32 MB (b,n,512) bf16
  u16*  expkT = (u16*)(ws + 67108864L);       // 32 MB (b,512,n) bf16
  u16*  vT    = (u16*)(ws + 100663296L);      // 32 MB (b,512,n) bf16
  u16*  wqkvT = (u16*)(ws + 134217728L);      // 1.5 MB
  u16*  Mt    = (u16*)(ws + 134217728L);      // 2 MB, reuses wqkvT region (after gemm1)
  float* S    = (float*)(ws + 136314880L);    // 8 KB
  float* ctx  = (float*)(ws + 0L);            // 512 KB, aliases h (dead after gemm1)
  float* Z    = (float*)d_out;                // 1 MB, holds 1/Z (written by gemm1), dead before gemm_tn_f

  transpose_f2b<<<dim3(24, 8), 256, 0, stream>>>(wqkv, wqkvT, 512, 1536, S);

  ln_kernel<<<dim3(256, 4), 256, 0, stream>>>(x, lnw, lnb, h);

  gemm1<<<dim3(12, 256), 256, 0, stream>>>(h, wqkvT, qexp, expkT, vT, S, Z);

  hipMemsetAsync(ctx, 0, 4 * 8 * 64 * 64 * 4, stream);

  ctx_kernel<<<dim3(16, 8, 4), 256, 0, stream>>>(expkT, vT, Z, ctx);

  mprime<<<dim3(8, 8, 4), 256, 0, stream>>>(ctx, wout, S, Mt);

  gemm_tn_f<<<dim3(4, 64, 4), 256, 0, stream>>>(Mt, qexp, out, bout, 512, 8192,
                                                262144L, (long)8192 * 512, (long)512 * 8192);
}

// Round 8
// 279.244 us; speedup vs baseline: 1.1688x; 1.0117x over previous
//
#include <hip/hip_runtime.h>

#define B_   4
#define N_   8192
#define D_   512
#define NH   8
#define DH   64
#define HID  512

typedef unsigned short u16;
typedef __attribute__((ext_vector_type(8))) short  bf16x8;
typedef __attribute__((ext_vector_type(8))) unsigned short u16x8;
typedef __attribute__((ext_vector_type(4))) float  f32x4;

__device__ __forceinline__ float bf2f(u16 u) {
  unsigned int i = ((unsigned int)u) << 16;
  return __builtin_bit_cast(float, i);
}
__device__ __forceinline__ u16 f2bf(float f) {
  unsigned int i = __builtin_bit_cast(unsigned int, f);
  i += 0x7fff + ((i >> 16) & 1);
  return (u16)(i >> 16);
}

#define GLOAD16(g, l) \
  __builtin_amdgcn_global_load_lds((const __attribute__((address_space(1))) void*)(g), \
                                   (__attribute__((address_space(3))) void*)(l), 16, 0, 0)

// ------------------------------------------------- tiled transpose fp32 -> bf16
// Also zeroes S (first 8 blocks) so the separate memset dispatch is dropped.
__global__ __launch_bounds__(256) void transpose_f2b(const float* __restrict__ in,
                                                     u16* __restrict__ out,
                                                     int rows, int cols,
                                                     float* __restrict__ S0) {
  __shared__ u16 tile[64][65];
  int c0 = blockIdx.x * 64, r0 = blockIdx.y * 64;
  int t = threadIdx.x;
  if (blockIdx.y == 0 && blockIdx.x < 8) S0[blockIdx.x * 256 + t] = 0.f;
  int rl = t >> 6, cl = t & 63;
#pragma unroll
  for (int i = 0; i < 16; i++) {
    int r = i * 4 + rl;
    tile[r][cl] = f2bf(in[(long)(r0 + r) * cols + c0 + cl]);
  }
  __syncthreads();
  int c4 = t >> 6, rr = t & 63;
#pragma unroll
  for (int i = 0; i < 16; i++) {
    int c = i * 4 + c4;
    out[(long)(c0 + c) * rows + r0 + rr] = tile[rr][c];
  }
}

// ------------------------------------------------- layernorm, single HBM pass
__global__ __launch_bounds__(256) void ln_kernel(const float* __restrict__ x,
                                                 const float* __restrict__ lw,
                                                 const float* __restrict__ lb,
                                                 u16* __restrict__ h) {
  __shared__ u16 xs[32 * 520];
  __shared__ float red[2][8][32];
  __shared__ float murs[2][32];
  __shared__ float lws[512], lbs[512];
  int b = blockIdx.y, n0 = blockIdx.x * 32;
  int t = threadIdx.x;
  lws[t] = lw[t]; lws[t + 256] = lw[t + 256];
  lbs[t] = lb[t]; lbs[t + 256] = lb[t + 256];
  int tok = t & 31, dp = t >> 5;
  const float* xp = x + (long)b * D_ * N_ + n0 + tok;
  float s = 0.f, s2 = 0.f;
#pragma unroll 8
  for (int i = 0; i < 64; i++) {
    int d = dp * 64 + i;
    float v = xp[(long)d * N_];
    s += v; s2 += v * v;
    xs[tok * 520 + d] = f2bf(v);
  }
  red[0][dp][tok] = s; red[1][dp][tok] = s2;
  __syncthreads();
  if (t < 32) {
    float S1 = 0.f, S2 = 0.f;
#pragma unroll
    for (int i = 0; i < 8; i++) { S1 += red[0][i][t]; S2 += red[1][i][t]; }
    float mu = S1 * (1.0f / 512.0f);
    float var = S2 * (1.0f / 512.0f) - mu * mu;
    murs[0][t] = mu; murs[1][t] = rsqrtf(var + 1e-5f);
  }
  __syncthreads();
  int row = t >> 3, seg = t & 7;
  float mu = murs[0][row], rs = murs[1][row];
  u16* hp = h + ((long)b * N_ + n0 + row) * D_;
  const u16* xr = xs + row * 520;
#pragma unroll
  for (int c = 0; c < 8; c++) {
    int d0 = c * 64 + seg * 8;
    u16x8 in8 = *(const u16x8*)(xr + d0);
    u16x8 o;
#pragma unroll
    for (int i = 0; i < 8; i++) {
      int d = d0 + i;
      o[i] = f2bf((bf2f(in8[i]) - mu) * rs * lws[d] + lbs[d]);
    }
    *(u16x8*)(hp + d0) = o;
  }
}

// ------------------------------------------------- GEMM1: h @ wqkv with fused softmax prep
// 4-buffer ring K-loop, depth-3 prefetch, counted vmcnt (never drains global
// loads in steady state). Per-iteration wait is vmcnt(8) PLUS lgkmcnt(0):
// the lgkmcnt(0) drain before each barrier is MANDATORY — without it a wave can
// cross the barrier with ds_reads of buf (tt&3) still in flight (compiler may
// sink register-only MFMAs + their lgkm waits past inline-asm/barrier, rule #18),
// and the next iteration's STAGE overwrites that buffer => silent corruption
// (R7 failure: absmax 1.05e-2). vmcnt(8) = 2 tiles x 4 loads/wave in flight.
// NOTE (R3-R5 lesson): 256²/512-thread variant spills; keep 128²/256-thread.
__global__ __launch_bounds__(256) void gemm1(const u16* __restrict__ A,
                                             const u16* __restrict__ B,
                                             u16* __restrict__ qexp,
                                             u16* __restrict__ expkT,
                                             u16* __restrict__ vT,
                                             float* __restrict__ S,
                                             float* __restrict__ Z) {
  const int K = 512;
  // ring: 4 bufs x (As 4096 | Bs 4096) u16 = 64KB; epilogue Cs = 17408 u16 aliases
  __shared__ alignas(16) u16 smem[32768];

  // XCD-chunked swizzle: nwg = 3072, 384 contiguous work-ids per XCD.
  int bid = blockIdx.y * 12 + blockIdx.x;
  int wid = (bid & 7) * 384 + (bid >> 3);
  int bx = wid % 12, by = wid / 12;
  int m0 = by * 128, n0 = bx * 128;

  int tid = threadIdx.x, wave = tid >> 6, lane = tid & 63;
  int l15 = lane & 15, qd = lane >> 4;

  int ra0 = tid >> 2,          qa0 = (tid & 3) ^ ((ra0 >> 1) & 3);
  int ra1 = (tid + 256) >> 2,  qa1 = (tid & 3) ^ ((ra1 >> 1) & 3);
  const u16* gA0 = A + (long)(m0 + ra0) * K + qa0 * 8;
  const u16* gA1 = A + (long)(m0 + ra1) * K + qa1 * 8;
  const u16* gB0 = B + (long)(n0 + ra0) * K + qa0 * 8;
  const u16* gB1 = B + (long)(n0 + ra1) * K + qa1 * 8;

  int wm = wave & 1, wn = wave >> 1;
  int aoff[4], boff[4];
#pragma unroll
  for (int i = 0; i < 4; i++) {
    int r = wm * 64 + i * 16 + l15;
    aoff[i] = r * 32 + ((qd ^ ((r >> 1) & 3)) * 8);
    int rb = wn * 64 + i * 16 + l15;
    boff[i] = rb * 32 + ((qd ^ ((rb >> 1) & 3)) * 8);
  }

  f32x4 zero = {0.f, 0.f, 0.f, 0.f};
  f32x4 acc[4][4];
#pragma unroll
  for (int i = 0; i < 4; i++)
#pragma unroll
    for (int j = 0; j < 4; j++) acc[i][j] = zero;

#define STAGE1(buf, kt) { \
    u16* dA = smem + (buf) * 8192 + wave * 512; \
    u16* dB = smem + (buf) * 8192 + 4096 + wave * 512; \
    GLOAD16(gA0 + (kt) * 32, dA); GLOAD16(gA1 + (kt) * 32, dA + 2048); \
    GLOAD16(gB0 + (kt) * 32, dB); GLOAD16(gB1 + (kt) * 32, dB + 2048); }

  // prologue: stage T0,T1,T2 (12 loads/wave); wait T0 only
  STAGE1(0, 0); STAGE1(1, 1); STAGE1(2, 2);
  asm volatile("s_waitcnt vmcnt(8)" ::: "memory");
  __builtin_amdgcn_s_barrier();

#pragma unroll
  for (int tt = 0; tt < 16; tt++) {
    if (tt < 13) STAGE1((tt + 3) & 3, tt + 3);   // issue-early; 3 tiles in flight
    const u16* Ac = smem + (tt & 3) * 8192;
    const u16* Bc = smem + (tt & 3) * 8192 + 4096;
    bf16x8 af[4], bf[4];
#pragma unroll
    for (int q = 0; q < 4; q++) {
      af[q] = *(const bf16x8*)(Ac + aoff[q]);
      bf[q] = *(const bf16x8*)(Bc + boff[q]);
    }
#pragma unroll
    for (int i = 0; i < 4; i++)
#pragma unroll
      for (int j = 0; j < 4; j++)
        acc[i][j] = __builtin_amdgcn_mfma_f32_16x16x32_bf16(af[i], bf[j], acc[i][j], 0, 0, 0);
    if (tt < 13)       { asm volatile("s_waitcnt vmcnt(8) lgkmcnt(0)" ::: "memory"); __builtin_amdgcn_s_barrier(); }
    else if (tt == 13) { asm volatile("s_waitcnt vmcnt(4) lgkmcnt(0)" ::: "memory"); __builtin_amdgcn_s_barrier(); }
    else if (tt == 14) { asm volatile("s_waitcnt vmcnt(0) lgkmcnt(0)" ::: "memory"); __builtin_amdgcn_s_barrier(); }
  }
  asm volatile("s_waitcnt vmcnt(0) lgkmcnt(0)" ::: "memory");
  __builtin_amdgcn_s_barrier();            // all reads done; safe to overwrite smem with Cs
#undef STAGE1

  u16* Cs = smem;                          // epilogue staging aliases the ring buffers

  int third = n0 >> 9;
  int n0t = n0 & 511;
  int b = m0 >> 13;
  int tloc = m0 & 8191;

  if (third == 0) {
#pragma unroll
    for (int i = 0; i < 4; i++)
#pragma unroll
      for (int j = 0; j < 4; j++)
#pragma unroll
        for (int r = 0; r < 4; r++) acc[i][j][r] = __expf(acc[i][j][r] * 0.125f);
#pragma unroll
    for (int j = 0; j < 4; j++) {
      float ps = 0.f;
#pragma unroll
      for (int i = 0; i < 4; i++)
#pragma unroll
        for (int r = 0; r < 4; r++) ps += acc[i][j][r];
      ps += __shfl_xor(ps, 16);
      ps += __shfl_xor(ps, 32);
      if (qd == 0) atomicAdd(S + b * 512 + n0t + wn * 64 + j * 16 + l15, ps);
    }
  } else if (third == 1) {
#pragma unroll
    for (int i = 0; i < 4; i++)
#pragma unroll
      for (int j = 0; j < 4; j++)
#pragma unroll
        for (int r = 0; r < 4; r++) acc[i][j][r] = __expf(acc[i][j][r]);
    int head = (n0t >> 6) + wn;
#pragma unroll
    for (int i = 0; i < 4; i++)
#pragma unroll
      for (int r = 0; r < 4; r++) {
        float rs = acc[i][0][r] + acc[i][1][r] + acc[i][2][r] + acc[i][3][r];
        rs += __shfl_xor(rs, 1);
        rs += __shfl_xor(rs, 2);
        rs += __shfl_xor(rs, 4);
        rs += __shfl_xor(rs, 8);
        // single-writer per Z element: direct reciprocal store (no atomic/memset/zrecip)
        if (l15 == 0)
          Z[((long)b * NH + head) * 8192 + tloc + wm * 64 + i * 16 + qd * 4 + r] = 1.0f / rs;
      }
  }

  if (third == 0) {
#pragma unroll
    for (int i = 0; i < 4; i++)
#pragma unroll
      for (int r = 0; r < 4; r++)
#pragma unroll
        for (int j = 0; j < 4; j++)
          Cs[(wm * 64 + i * 16 + qd * 4 + r) * 136 + wn * 64 + j * 16 + l15] =
              f2bf(acc[i][j][r]);
  } else {
#pragma unroll
    for (int i = 0; i < 4; i++)
#pragma unroll
      for (int r = 0; r < 4; r++)
#pragma unroll
        for (int j = 0; j < 4; j++)
          Cs[(wn * 64 + j * 16 + l15) * 136 + wm * 64 + i * 16 + qd * 4 + r] =
              f2bf(acc[i][j][r]);
  }
  __syncthreads();

  u16* dst; long ldg;
  if (third == 0)      { dst = qexp  + ((long)b * N_ + tloc) * 512 + n0t;  ldg = 512; }
  else if (third == 1) { dst = expkT + ((long)b * 512 + n0t) * 8192 + tloc; ldg = 8192; }
  else                 { dst = vT    + ((long)b * 512 + n0t) * 8192 + tloc; ldg = 8192; }

  // full-line stores: 8 lanes cover 128B contiguous of one row per instruction
  int seg = lane & 7;
#pragma unroll
  for (int outer = 0; outer < 2; outer++)
#pragma unroll
    for (int rr = 0; rr < 2; rr++) {
      int row = outer * 64 + wave * 16 + rr * 8 + (lane >> 3);
      const u16* src = Cs + row * 136;
      u16* dp = dst + (long)row * ldg;
#pragma unroll
      for (int p = 0; p < 2; p++)
        *(uint4*)(dp + p * 64 + seg * 8) = *(const uint4*)(src + p * 64 + seg * 8);
    }
}

// ------------------------------------------------- ctx[b,h,d,e] += sum_n expkT[d,n] * vT[e,n] * Zr[b,h,n]
// Zr already holds reciprocals (written by gemm1).
__global__ __launch_bounds__(256) void ctx_kernel(const u16* __restrict__ expkT,
                                                  const u16* __restrict__ vT,
                                                  const float* __restrict__ Zr,
                                                  float* __restrict__ ctx) {
  __shared__ u16 As[64 * 128];
  __shared__ u16 Bs[64 * 128];
  int kc = blockIdx.x, hh = blockIdx.y, b = blockIdx.z;
  int t = threadIdx.x, w = t >> 6, l = t & 63, l15 = l & 15, qd = l >> 4;
  long nbase = (long)kc * 512;
  const u16* Abase = expkT + ((long)b * 512 + hh * 64) * 8192 + nbase;
  const u16* Bbase = vT   + ((long)b * 512 + hh * 64) * 8192 + nbase;
  const float* Zb = Zr + ((long)b * NH + hh) * 8192 + nbase;

  f32x4 zero = {0.f, 0.f, 0.f, 0.f};
  f32x4 acc[4] = {zero, zero, zero, zero};

  int brow = t >> 2;
  for (int s = 0; s < 4; s++) {
    long ko = (long)s * 128;
    __syncthreads();
#pragma unroll
    for (int si = 0; si < 4; si++) {
      int qq = si * 4 + w;
      int row = qq * 4 + (l >> 4);
      int gs = (l & 15) ^ (row & 15);
      GLOAD16(Abase + (long)row * 8192 + ko + gs * 8, As + qq * 512);
    }
    {
      const u16* src = Bbase + (long)brow * 8192 + ko;
#pragma unroll
      for (int cc = 0; cc < 4; cc++) {
        int c = (t & 3) * 4 + cc;
        u16x8 v8 = *(const u16x8*)(src + c * 8);
        float4 z0 = *(const float4*)(Zb + ko + c * 8);
        float4 z1 = *(const float4*)(Zb + ko + c * 8 + 4);
        u16x8 o;
        o[0] = f2bf(bf2f(v8[0]) * z0.x); o[1] = f2bf(bf2f(v8[1]) * z0.y);
        o[2] = f2bf(bf2f(v8[2]) * z0.z); o[3] = f2bf(bf2f(v8[3]) * z0.w);
        o[4] = f2bf(bf2f(v8[4]) * z1.x); o[5] = f2bf(bf2f(v8[5]) * z1.y);
        o[6] = f2bf(bf2f(v8[6]) * z1.z); o[7] = f2bf(bf2f(v8[7]) * z1.w);
        *(u16x8*)(Bs + brow * 128 + ((c ^ (brow & 15)) * 8)) = o;
      }
    }
    __syncthreads();
#pragma unroll
    for (int kk = 0; kk < 4; kk++) {
      int ar = w * 16 + l15;
      bf16x8 af = *(const bf16x8*)(As + ar * 128 + (((kk * 4 + qd) ^ (ar & 15)) * 8));
#pragma unroll
      for (int j = 0; j < 4; j++) {
        int br = j * 16 + l15;
        bf16x8 bf8 = *(const bf16x8*)(Bs + br * 128 + (((kk * 4 + qd) ^ (br & 15)) * 8));
        acc[j] = __builtin_amdgcn_mfma_f32_16x16x32_bf16(af, bf8, acc[j], 0, 0, 0);
      }
    }
  }
  float* cp = ctx + ((long)(b * NH + hh)) * DH * DH;
#pragma unroll
  for (int j = 0; j < 4; j++)
#pragma unroll
    for (int r = 0; r < 4; r++)
      atomicAdd(cp + (w * 16 + qd * 4 + r) * 64 + j * 16 + l15, acc[j][r]);
}

// ------------------------------------------------- mprime
__global__ __launch_bounds__(256) void mprime(const float* __restrict__ ctx,
                                              const float* __restrict__ wout,
                                              const float* __restrict__ S,
                                              u16* __restrict__ Mt) {
  __shared__ float ws[64 * 65];
  __shared__ float cs[64 * 65];
  int dt = blockIdx.x, hh = blockIdx.y, b = blockIdx.z;
  int t = threadIdx.x;
  {
    int e = t >> 2;
#pragma unroll
    for (int ii = 0; ii < 4; ii++) {
      int col = (t & 3) * 16 + ii * 4;
      float4 v = *(const float4*)(wout + (long)(hh * 64 + e) * 512 + dt * 64 + col);
      ws[e * 65 + col] = v.x; ws[e * 65 + col + 1] = v.y;
      ws[e * 65 + col + 2] = v.z; ws[e * 65 + col + 3] = v.w;
      float4 c = *(const float4*)(ctx + ((long)(b * NH + hh)) * 4096 + (long)e * 64 + col);
      cs[e * 65 + col] = c.x; cs[e * 65 + col + 1] = c.y;
      cs[e * 65 + col + 2] = c.z; cs[e * 65 + col + 3] = c.w;
    }
  }
  __syncthreads();
  int dol = t & 63, dg = t >> 6;
#pragma unroll
  for (int dd = 0; dd < 16; dd++) {
    int d = dg * 16 + dd;
    float v = 0.f;
#pragma unroll 8
    for (int e = 0; e < 64; e++) v += cs[d * 65 + e] * ws[e * 65 + dol];
    float sv = S[b * 512 + hh * 64 + d];
    Mt[(long)b * 262144 + (long)(dt * 64 + dol) * 512 + hh * 64 + d] = f2bf(v / sv);
  }
}

// ------------------------------------------------- GEMM2 (TN), fp32 out + bias
// Same 4-buffer ring + counted vmcnt + lgkmcnt(0) drain as gemm1.
__global__ __launch_bounds__(256) void gemm_tn_f(const u16* __restrict__ A,
                                                 const u16* __restrict__ B,
                                                 float* __restrict__ C,
                                                 const float* __restrict__ bias,
                                                 int K, int ldc,
                                                 long sA, long sB, long sC) {
  // ring 64KB; epilogue Cf = 64*133 f32 = 34048B aliases
  __shared__ alignas(16) u16 smem[32768];
  float* Cf = (float*)smem;

  // XCD-chunked swizzle: nwg = 1024, 128 contiguous work-ids per XCD.
  int bid = (blockIdx.z * gridDim.y + blockIdx.y) * gridDim.x + blockIdx.x;
  int wid = (bid & 7) * 128 + (bid >> 3);
  int mx = wid & 3;
  int ny = (wid >> 2) & 63;
  long bz = wid >> 8;
  A += bz * sA; B += bz * sB; C += bz * sC;
  int m0 = mx * 128, n0 = ny * 128;

  int tid = threadIdx.x, wave = tid >> 6, lane = tid & 63;
  int l15 = lane & 15, qd = lane >> 4;

  int ra0 = tid >> 2,          qa0 = (tid & 3) ^ ((ra0 >> 1) & 3);
  int ra1 = (tid + 256) >> 2,  qa1 = (tid & 3) ^ ((ra1 >> 1) & 3);
  const u16* gA0 = A + (long)(m0 + ra0) * K + qa0 * 8;
  const u16* gA1 = A + (long)(m0 + ra1) * K + qa1 * 8;
  const u16* gB0 = B + (long)(n0 + ra0) * K + qa0 * 8;
  const u16* gB1 = B + (long)(n0 + ra1) * K + qa1 * 8;

  int wm = wave & 1, wn = wave >> 1;
  int aoff[4], boff[4];
#pragma unroll
  for (int i = 0; i < 4; i++) {
    int r = wm * 64 + i * 16 + l15;
    aoff[i] = r * 32 + ((qd ^ ((r >> 1) & 3)) * 8);
    int rb = wn * 64 + i * 16 + l15;
    boff[i] = rb * 32 + ((qd ^ ((rb >> 1) & 3)) * 8);
  }

  f32x4 zero = {0.f, 0.f, 0.f, 0.f};
  f32x4 acc[4][4];
#pragma unroll
  for (int i = 0; i < 4; i++)
#pragma unroll
    for (int j = 0; j < 4; j++) acc[i][j] = zero;

#define STAGE2(buf, kt) { \
    u16* dA = smem + (buf) * 8192 + wave * 512; \
    u16* dB = smem + (buf) * 8192 + 4096 + wave * 512; \
    GLOAD16(gA0 + (kt) * 32, dA); GLOAD16(gA1 + (kt) * 32, dA + 2048); \
    GLOAD16(gB0 + (kt) * 32, dB); GLOAD16(gB1 + (kt) * 32, dB + 2048); }

  STAGE2(0, 0); STAGE2(1, 1); STAGE2(2, 2);
  asm volatile("s_waitcnt vmcnt(8)" ::: "memory");
  __builtin_amdgcn_s_barrier();

#pragma unroll
  for (int tt = 0; tt < 16; tt++) {
    if (tt < 13) STAGE2((tt + 3) & 3, tt + 3);
    const u16* Ac = smem + (tt & 3) * 8192;
    const u16* Bc = smem + (tt & 3) * 8192 + 4096;
    bf16x8 af[4], bf[4];
#pragma unroll
    for (int q = 0; q < 4; q++) {
      af[q] = *(const bf16x8*)(Ac + aoff[q]);
      bf[q] = *(const bf16x8*)(Bc + boff[q]);
    }
#pragma unroll
    for (int i = 0; i < 4; i++)
#pragma unroll
      for (int j = 0; j < 4; j++)
        acc[i][j] = __builtin_amdgcn_mfma_f32_16x16x32_bf16(af[i], bf[j], acc[i][j], 0, 0, 0);
    if (tt < 13)       { asm volatile("s_waitcnt vmcnt(8) lgkmcnt(0)" ::: "memory"); __builtin_amdgcn_s_barrier(); }
    else if (tt == 13) { asm volatile("s_waitcnt vmcnt(4) lgkmcnt(0)" ::: "memory"); __builtin_amdgcn_s_barrier(); }
    else if (tt == 14) { asm volatile("s_waitcnt vmcnt(0) lgkmcnt(0)" ::: "memory"); __builtin_amdgcn_s_barrier(); }
  }
  asm volatile("s_waitcnt vmcnt(0) lgkmcnt(0)" ::: "memory");
  __builtin_amdgcn_s_barrier();
#undef STAGE2

#pragma unroll
  for (int half = 0; half < 2; half++) {
    __syncthreads();
    if (wm == half) {
#pragma unroll
      for (int i = 0; i < 4; i++)
#pragma unroll
        for (int r = 0; r < 4; r++) {
          int rrl = i * 16 + qd * 4 + r;
          float bv = bias[m0 + half * 64 + rrl];
#pragma unroll
          for (int j = 0; j < 4; j++)
            Cf[rrl * 133 + wn * 64 + j * 16 + l15] = acc[i][j][r] + bv;
        }
    }
    __syncthreads();
#pragma unroll
    for (int z = 0; z < 2; z++) {
      int rrl = z * 32 + (tid >> 3);
      int seg = tid & 7;
      float* dp = C + (long)(m0 + half * 64 + rrl) * ldc + n0;
      const float* src = Cf + rrl * 133;
#pragma unroll
      for (int p = 0; p < 4; p++)
        *(float4*)(dp + p * 32 + seg * 4) = *(const float4*)(src + p * 32 + seg * 4);
    }
  }
}

// ------------------------------------------------- launch
extern "C" void kernel_launch(void* const* d_in, const int* in_sizes, int n_in,
                              void* d_out, int out_size, void* d_ws, size_t ws_size,
                              hipStream_t stream) {
  const float* x    = (const float*)d_in[0];
  const float* lnw  = (const float*)d_in[1];
  const float* lnb  = (const float*)d_in[2];
  const float* wqkv = (const float*)d_in[3];
  const float* wout = (const float*)d_in[4];
  const float* bout = (const float*)d_in[5];
  float* out = (float*)d_out;
  char* ws = (char*)d_ws;

  u16*  h     = (u16*)(ws + 0L);              // 32 MB (b,n,d) bf16
  u16*  qexp  = (u16*)(ws + 33554432L);       // 32 MB (b,n,512) bf16
  u16*  expkT = (u16*)(ws + 67108864L);       // 32 MB (b,512,n) bf16
  u16*  vT    = (u16*)(ws + 100663296L);      // 32 MB (b,512,n) bf16
  u16*  wqkvT = (u16*)(ws + 134217728L);      // 1.5 MB
  u16*  Mt    = (u16*)(ws + 134217728L);      // 2 MB, reuses wqkvT region (after gemm1)
  float* S    = (float*)(ws + 136314880L);    // 8 KB
  float* ctx  = (float*)(ws + 0L);            // 512 KB, aliases h (dead after gemm1)
  float* Z    = (float*)d_out;                // 1 MB, holds 1/Z (written by gemm1), dead before gemm_tn_f

  transpose_f2b<<<dim3(24, 8), 256, 0, stream>>>(wqkv, wqkvT, 512, 1536, S);

  ln_kernel<<<dim3(256, 4), 256, 0, stream>>>(x, lnw, lnb, h);

  gemm1<<<dim3(12, 256), 256, 0, stream>>>(h, wqkvT, qexp, expkT, vT, S, Z);

  hipMemsetAsync(ctx, 0, 4 * 8 * 64 * 64 * 4, stream);

  ctx_kernel<<<dim3(16, 8, 4), 256, 0, stream>>>(expkT, vT, Z, ctx);

  mprime<<<dim3(8, 8, 4), 256, 0, stream>>>(ctx, wout, S, Mt);

  gemm_tn_f<<<dim3(4, 64, 4), 256, 0, stream>>>(Mt, qexp, out, bout, 512, 8192,
                                                262144L, (long)8192 * 512, (long)512 * 8192);
}

// Round 9
// 276.399 us; speedup vs baseline: 1.1808x; 1.0103x over previous
//
#include <hip/hip_runtime.h>

#define B_   4
#define N_   8192
#define D_   512
#define NH   8
#define DH   64
#define HID  512

typedef unsigned short u16;
typedef __attribute__((ext_vector_type(8))) short  bf16x8;
typedef __attribute__((ext_vector_type(8))) unsigned short u16x8;
typedef __attribute__((ext_vector_type(4))) float  f32x4;

__device__ __forceinline__ float bf2f(u16 u) {
  unsigned int i = ((unsigned int)u) << 16;
  return __builtin_bit_cast(float, i);
}
__device__ __forceinline__ u16 f2bf(float f) {
  unsigned int i = __builtin_bit_cast(unsigned int, f);
  i += 0x7fff + ((i >> 16) & 1);
  return (u16)(i >> 16);
}

#define GLOAD16(g, l) \
  __builtin_amdgcn_global_load_lds((const __attribute__((address_space(1))) void*)(g), \
                                   (__attribute__((address_space(3))) void*)(l), 16, 0, 0)

// ------------------------------------------------- tiled transpose fp32 -> bf16
// Also zeroes S (first 8 blocks) so the separate memset dispatch is dropped.
__global__ __launch_bounds__(256) void transpose_f2b(const float* __restrict__ in,
                                                     u16* __restrict__ out,
                                                     int rows, int cols,
                                                     float* __restrict__ S0) {
  __shared__ u16 tile[64][65];
  int c0 = blockIdx.x * 64, r0 = blockIdx.y * 64;
  int t = threadIdx.x;
  if (blockIdx.y == 0 && blockIdx.x < 8) S0[blockIdx.x * 256 + t] = 0.f;
  int rl = t >> 6, cl = t & 63;
#pragma unroll
  for (int i = 0; i < 16; i++) {
    int r = i * 4 + rl;
    tile[r][cl] = f2bf(in[(long)(r0 + r) * cols + c0 + cl]);
  }
  __syncthreads();
  int c4 = t >> 6, rr = t & 63;
#pragma unroll
  for (int i = 0; i < 16; i++) {
    int c = i * 4 + c4;
    out[(long)(c0 + c) * rows + r0 + rr] = tile[rr][c];
  }
}

// ------------------------------------------------- layernorm, single HBM pass
// float4-vectorized x reads (G13): 8 lanes x float4 = 32 tokens, 32 d-groups of 16.
// Each lane accumulates 4 token partial sums in registers; LDS reduce over 32 groups.
__global__ __launch_bounds__(256) void ln_kernel(const float* __restrict__ x,
                                                 const float* __restrict__ lw,
                                                 const float* __restrict__ lb,
                                                 u16* __restrict__ h) {
  __shared__ u16 xs[32 * 520];
  __shared__ float red[2][32][32];
  __shared__ float murs[2][32];
  __shared__ float lws[512], lbs[512];
  int b = blockIdx.y, n0 = blockIdx.x * 32;
  int t = threadIdx.x;
  lws[t] = lw[t]; lws[t + 256] = lw[t + 256];
  lbs[t] = lb[t]; lbs[t + 256] = lb[t + 256];
  int tok4 = (t & 7) * 4;                    // this lane's 4 tokens
  int dg = t >> 3;                           // 0..31 d-group (16 d each)
  const float* xp = x + (long)b * D_ * N_ + n0 + tok4;
  float s0 = 0.f, s1 = 0.f, sB = 0.f, sC = 0.f;
  float q0 = 0.f, q1 = 0.f, qB = 0.f, qC = 0.f;
#pragma unroll
  for (int i = 0; i < 16; i++) {
    int d = dg * 16 + i;
    float4 v = *(const float4*)(xp + (long)d * N_);
    s0 += v.x; q0 += v.x * v.x;
    s1 += v.y; q1 += v.y * v.y;
    sB += v.z; qB += v.z * v.z;
    sC += v.w; qC += v.w * v.w;
    xs[(tok4 + 0) * 520 + d] = f2bf(v.x);
    xs[(tok4 + 1) * 520 + d] = f2bf(v.y);
    xs[(tok4 + 2) * 520 + d] = f2bf(v.z);
    xs[(tok4 + 3) * 520 + d] = f2bf(v.w);
  }
  red[0][dg][tok4 + 0] = s0; red[1][dg][tok4 + 0] = q0;
  red[0][dg][tok4 + 1] = s1; red[1][dg][tok4 + 1] = q1;
  red[0][dg][tok4 + 2] = sB; red[1][dg][tok4 + 2] = qB;
  red[0][dg][tok4 + 3] = sC; red[1][dg][tok4 + 3] = qC;
  __syncthreads();
  if (t < 32) {
    float S1 = 0.f, S2 = 0.f;
#pragma unroll
    for (int i = 0; i < 32; i++) { S1 += red[0][i][t]; S2 += red[1][i][t]; }
    float mu = S1 * (1.0f / 512.0f);
    float var = S2 * (1.0f / 512.0f) - mu * mu;
    murs[0][t] = mu; murs[1][t] = rsqrtf(var + 1e-5f);
  }
  __syncthreads();
  int row = t >> 3, seg = t & 7;
  float mu = murs[0][row], rs = murs[1][row];
  u16* hp = h + ((long)b * N_ + n0 + row) * D_;
  const u16* xr = xs + row * 520;
#pragma unroll
  for (int c = 0; c < 8; c++) {
    int d0 = c * 64 + seg * 8;
    u16x8 in8 = *(const u16x8*)(xr + d0);
    u16x8 o;
#pragma unroll
    for (int i = 0; i < 8; i++) {
      int d = d0 + i;
      o[i] = f2bf((bf2f(in8[i]) - mu) * rs * lws[d] + lbs[d]);
    }
    *(u16x8*)(hp + d0) = o;
  }
}

// ------------------------------------------------- GEMM1: h @ wqkv with fused softmax prep
// 3-buffer ring (48KB), depth-2 prefetch, counted vmcnt(4)+lgkmcnt(0) per iter
// (lgkm drain before each barrier MANDATORY — R7 race, rule #18).
// __launch_bounds__(256,3): wave cost was 108 arch + 64 acc = 172 regs -> only
// 2 waves/SIMD from the ~512-reg pool; clamping arch to ~106 fits 3 waves/SIMD
// (170 budget) = +50% TLP on this latency-bound loop. LDS 48KB -> 3 blocks/CU.
// NOTE (R3-R5): 256²/512-thread variant spills massively; keep 128²/256-thread.
__global__ __launch_bounds__(256, 3) void gemm1(const u16* __restrict__ A,
                                                const u16* __restrict__ B,
                                                u16* __restrict__ qexp,
                                                u16* __restrict__ expkT,
                                                u16* __restrict__ vT,
                                                float* __restrict__ S,
                                                float* __restrict__ Z) {
  const int K = 512;
  // ring: 3 bufs x (As 4096 | Bs 4096) u16 = 48KB; epilogue Cs = 17408 u16 aliases
  __shared__ alignas(16) u16 smem[24576];

  // XCD-chunked swizzle: nwg = 3072, 384 contiguous work-ids per XCD.
  int bid = blockIdx.y * 12 + blockIdx.x;
  int wid = (bid & 7) * 384 + (bid >> 3);
  int bx = wid % 12, by = wid / 12;
  int m0 = by * 128, n0 = bx * 128;

  int tid = threadIdx.x, wave = tid >> 6, lane = tid & 63;
  int l15 = lane & 15, qd = lane >> 4;

  int ra0 = tid >> 2,          qa0 = (tid & 3) ^ ((ra0 >> 1) & 3);
  int ra1 = (tid + 256) >> 2,  qa1 = (tid & 3) ^ ((ra1 >> 1) & 3);
  const u16* gA0 = A + (long)(m0 + ra0) * K + qa0 * 8;
  const u16* gA1 = A + (long)(m0 + ra1) * K + qa1 * 8;
  const u16* gB0 = B + (long)(n0 + ra0) * K + qa0 * 8;
  const u16* gB1 = B + (long)(n0 + ra1) * K + qa1 * 8;

  int wm = wave & 1, wn = wave >> 1;
  int aoff[4], boff[4];
#pragma unroll
  for (int i = 0; i < 4; i++) {
    int r = wm * 64 + i * 16 + l15;
    aoff[i] = r * 32 + ((qd ^ ((r >> 1) & 3)) * 8);
    int rb = wn * 64 + i * 16 + l15;
    boff[i] = rb * 32 + ((qd ^ ((rb >> 1) & 3)) * 8);
  }

  f32x4 zero = {0.f, 0.f, 0.f, 0.f};
  f32x4 acc[4][4];
#pragma unroll
  for (int i = 0; i < 4; i++)
#pragma unroll
    for (int j = 0; j < 4; j++) acc[i][j] = zero;

#define STAGE1(buf, kt) { \
    u16* dA = smem + (buf) * 8192 + wave * 512; \
    u16* dB = smem + (buf) * 8192 + 4096 + wave * 512; \
    GLOAD16(gA0 + (kt) * 32, dA); GLOAD16(gA1 + (kt) * 32, dA + 2048); \
    GLOAD16(gB0 + (kt) * 32, dB); GLOAD16(gB1 + (kt) * 32, dB + 2048); }

  // prologue: stage T0,T1 (8 loads/wave); wait T0 only
  STAGE1(0, 0); STAGE1(1, 1);
  asm volatile("s_waitcnt vmcnt(4)" ::: "memory");
  __builtin_amdgcn_s_barrier();

#pragma unroll
  for (int tt = 0; tt < 16; tt++) {
    if (tt < 14) STAGE1((tt + 2) % 3, tt + 2);   // issue-early; 2 tiles in flight
    const u16* Ac = smem + (tt % 3) * 8192;
    const u16* Bc = smem + (tt % 3) * 8192 + 4096;
    bf16x8 af[4], bf[4];
#pragma unroll
    for (int q = 0; q < 4; q++) {
      af[q] = *(const bf16x8*)(Ac + aoff[q]);
      bf[q] = *(const bf16x8*)(Bc + boff[q]);
    }
#pragma unroll
    for (int i = 0; i < 4; i++)
#pragma unroll
      for (int j = 0; j < 4; j++)
        acc[i][j] = __builtin_amdgcn_mfma_f32_16x16x32_bf16(af[i], bf[j], acc[i][j], 0, 0, 0);
    if (tt < 14)       { asm volatile("s_waitcnt vmcnt(4) lgkmcnt(0)" ::: "memory"); __builtin_amdgcn_s_barrier(); }
    else if (tt == 14) { asm volatile("s_waitcnt vmcnt(0) lgkmcnt(0)" ::: "memory"); __builtin_amdgcn_s_barrier(); }
  }
  asm volatile("s_waitcnt vmcnt(0) lgkmcnt(0)" ::: "memory");
  __builtin_amdgcn_s_barrier();            // all reads done; safe to overwrite smem with Cs
#undef STAGE1

  u16* Cs = smem;                          // epilogue staging aliases the ring buffers

  int third = n0 >> 9;
  int n0t = n0 & 511;
  int b = m0 >> 13;
  int tloc = m0 & 8191;

  if (third == 0) {
#pragma unroll
    for (int i = 0; i < 4; i++)
#pragma unroll
      for (int j = 0; j < 4; j++)
#pragma unroll
        for (int r = 0; r < 4; r++) acc[i][j][r] = __expf(acc[i][j][r] * 0.125f);
#pragma unroll
    for (int j = 0; j < 4; j++) {
      float ps = 0.f;
#pragma unroll
      for (int i = 0; i < 4; i++)
#pragma unroll
        for (int r = 0; r < 4; r++) ps += acc[i][j][r];
      ps += __shfl_xor(ps, 16);
      ps += __shfl_xor(ps, 32);
      if (qd == 0) atomicAdd(S + b * 512 + n0t + wn * 64 + j * 16 + l15, ps);
    }
  } else if (third == 1) {
#pragma unroll
    for (int i = 0; i < 4; i++)
#pragma unroll
      for (int j = 0; j < 4; j++)
#pragma unroll
        for (int r = 0; r < 4; r++) acc[i][j][r] = __expf(acc[i][j][r]);
    int head = (n0t >> 6) + wn;
#pragma unroll
    for (int i = 0; i < 4; i++)
#pragma unroll
      for (int r = 0; r < 4; r++) {
        float rs = acc[i][0][r] + acc[i][1][r] + acc[i][2][r] + acc[i][3][r];
        rs += __shfl_xor(rs, 1);
        rs += __shfl_xor(rs, 2);
        rs += __shfl_xor(rs, 4);
        rs += __shfl_xor(rs, 8);
        // single-writer per Z element: direct reciprocal store (no atomic/memset/zrecip)
        if (l15 == 0)
          Z[((long)b * NH + head) * 8192 + tloc + wm * 64 + i * 16 + qd * 4 + r] = 1.0f / rs;
      }
  }

  if (third == 0) {
#pragma unroll
    for (int i = 0; i < 4; i++)
#pragma unroll
      for (int r = 0; r < 4; r++)
#pragma unroll
        for (int j = 0; j < 4; j++)
          Cs[(wm * 64 + i * 16 + qd * 4 + r) * 136 + wn * 64 + j * 16 + l15] =
              f2bf(acc[i][j][r]);
  } else {
#pragma unroll
    for (int i = 0; i < 4; i++)
#pragma unroll
      for (int r = 0; r < 4; r++)
#pragma unroll
        for (int j = 0; j < 4; j++)
          Cs[(wn * 64 + j * 16 + l15) * 136 + wm * 64 + i * 16 + qd * 4 + r] =
              f2bf(acc[i][j][r]);
  }
  __syncthreads();

  u16* dst; long ldg;
  if (third == 0)      { dst = qexp  + ((long)b * N_ + tloc) * 512 + n0t;  ldg = 512; }
  else if (third == 1) { dst = expkT + ((long)b * 512 + n0t) * 8192 + tloc; ldg = 8192; }
  else                 { dst = vT    + ((long)b * 512 + n0t) * 8192 + tloc; ldg = 8192; }

  // full-line stores: 8 lanes cover 128B contiguous of one row per instruction
  int seg = lane & 7;
#pragma unroll
  for (int outer = 0; outer < 2; outer++)
#pragma unroll
    for (int rr = 0; rr < 2; rr++) {
      int row = outer * 64 + wave * 16 + rr * 8 + (lane >> 3);
      const u16* src = Cs + row * 136;
      u16* dp = dst + (long)row * ldg;
#pragma unroll
      for (int p = 0; p < 2; p++)
        *(uint4*)(dp + p * 64 + seg * 8) = *(const uint4*)(src + p * 64 + seg * 8);
    }
}

// ------------------------------------------------- ctx[b,h,d,e] += sum_n expkT[d,n] * vT[e,n] * Zr[b,h,n]
// Zr already holds reciprocals (written by gemm1).
__global__ __launch_bounds__(256) void ctx_kernel(const u16* __restrict__ expkT,
                                                  const u16* __restrict__ vT,
                                                  const float* __restrict__ Zr,
                                                  float* __restrict__ ctx) {
  __shared__ u16 As[64 * 128];
  __shared__ u16 Bs[64 * 128];
  int kc = blockIdx.x, hh = blockIdx.y, b = blockIdx.z;
  int t = threadIdx.x, w = t >> 6, l = t & 63, l15 = l & 15, qd = l >> 4;
  long nbase = (long)kc * 512;
  const u16* Abase = expkT + ((long)b * 512 + hh * 64) * 8192 + nbase;
  const u16* Bbase = vT   + ((long)b * 512 + hh * 64) * 8192 + nbase;
  const float* Zb = Zr + ((long)b * NH + hh) * 8192 + nbase;

  f32x4 zero = {0.f, 0.f, 0.f, 0.f};
  f32x4 acc[4] = {zero, zero, zero, zero};

  int brow = t >> 2;
  for (int s = 0; s < 4; s++) {
    long ko = (long)s * 128;
    __syncthreads();
#pragma unroll
    for (int si = 0; si < 4; si++) {
      int qq = si * 4 + w;
      int row = qq * 4 + (l >> 4);
      int gs = (l & 15) ^ (row & 15);
      GLOAD16(Abase + (long)row * 8192 + ko + gs * 8, As + qq * 512);
    }
    {
      const u16* src = Bbase + (long)brow * 8192 + ko;
#pragma unroll
      for (int cc = 0; cc < 4; cc++) {
        int c = (t & 3) * 4 + cc;
        u16x8 v8 = *(const u16x8*)(src + c * 8);
        float4 z0 = *(const float4*)(Zb + ko + c * 8);
        float4 z1 = *(const float4*)(Zb + ko + c * 8 + 4);
        u16x8 o;
        o[0] = f2bf(bf2f(v8[0]) * z0.x); o[1] = f2bf(bf2f(v8[1]) * z0.y);
        o[2] = f2bf(bf2f(v8[2]) * z0.z); o[3] = f2bf(bf2f(v8[3]) * z0.w);
        o[4] = f2bf(bf2f(v8[4]) * z1.x); o[5] = f2bf(bf2f(v8[5]) * z1.y);
        o[6] = f2bf(bf2f(v8[6]) * z1.z); o[7] = f2bf(bf2f(v8[7]) * z1.w);
        *(u16x8*)(Bs + brow * 128 + ((c ^ (brow & 15)) * 8)) = o;
      }
    }
    __syncthreads();
#pragma unroll
    for (int kk = 0; kk < 4; kk++) {
      int ar = w * 16 + l15;
      bf16x8 af = *(const bf16x8*)(As + ar * 128 + (((kk * 4 + qd) ^ (ar & 15)) * 8));
#pragma unroll
      for (int j = 0; j < 4; j++) {
        int br = j * 16 + l15;
        bf16x8 bf8 = *(const bf16x8*)(Bs + br * 128 + (((kk * 4 + qd) ^ (br & 15)) * 8));
        acc[j] = __builtin_amdgcn_mfma_f32_16x16x32_bf16(af, bf8, acc[j], 0, 0, 0);
      }
    }
  }
  float* cp = ctx + ((long)(b * NH + hh)) * DH * DH;
#pragma unroll
  for (int j = 0; j < 4; j++)
#pragma unroll
    for (int r = 0; r < 4; r++)
      atomicAdd(cp + (w * 16 + qd * 4 + r) * 64 + j * 16 + l15, acc[j][r]);
}

// ------------------------------------------------- mprime
__global__ __launch_bounds__(256) void mprime(const float* __restrict__ ctx,
                                              const float* __restrict__ wout,
                                              const float* __restrict__ S,
                                              u16* __restrict__ Mt) {
  __shared__ float ws[64 * 65];
  __shared__ float cs[64 * 65];
  int dt = blockIdx.x, hh = blockIdx.y, b = blockIdx.z;
  int t = threadIdx.x;
  {
    int e = t >> 2;
#pragma unroll
    for (int ii = 0; ii < 4; ii++) {
      int col = (t & 3) * 16 + ii * 4;
      float4 v = *(const float4*)(wout + (long)(hh * 64 + e) * 512 + dt * 64 + col);
      ws[e * 65 + col] = v.x; ws[e * 65 + col + 1] = v.y;
      ws[e * 65 + col + 2] = v.z; ws[e * 65 + col + 3] = v.w;
      float4 c = *(const float4*)(ctx + ((long)(b * NH + hh)) * 4096 + (long)e * 64 + col);
      cs[e * 65 + col] = c.x; cs[e * 65 + col + 1] = c.y;
      cs[e * 65 + col + 2] = c.z; cs[e * 65 + col + 3] = c.w;
    }
  }
  __syncthreads();
  int dol = t & 63, dg = t >> 6;
#pragma unroll
  for (int dd = 0; dd < 16; dd++) {
    int d = dg * 16 + dd;
    float v = 0.f;
#pragma unroll 8
    for (int e = 0; e < 64; e++) v += cs[d * 65 + e] * ws[e * 65 + dol];
    float sv = S[b * 512 + hh * 64 + d];
    Mt[(long)b * 262144 + (long)(dt * 64 + dol) * 512 + hh * 64 + d] = f2bf(v / sv);
  }
}

// ------------------------------------------------- GEMM2 (TN), fp32 out + bias
// Same 3-buffer ring + counted vmcnt + lgkmcnt(0) + launch_bounds(256,3) as gemm1.
__global__ __launch_bounds__(256, 3) void gemm_tn_f(const u16* __restrict__ A,
                                                    const u16* __restrict__ B,
                                                    float* __restrict__ C,
                                                    const float* __restrict__ bias,
                                                    int K, int ldc,
                                                    long sA, long sB, long sC) {
  // ring 48KB; epilogue Cf = 64*133 f32 = 34048B aliases
  __shared__ alignas(16) u16 smem[24576];
  float* Cf = (float*)smem;

  // XCD-chunked swizzle: nwg = 1024, 128 contiguous work-ids per XCD.
  int bid = (blockIdx.z * gridDim.y + blockIdx.y) * gridDim.x + blockIdx.x;
  int wid = (bid & 7) * 128 + (bid >> 3);
  int mx = wid & 3;
  int ny = (wid >> 2) & 63;
  long bz = wid >> 8;
  A += bz * sA; B += bz * sB; C += bz * sC;
  int m0 = mx * 128, n0 = ny * 128;

  int tid = threadIdx.x, wave = tid >> 6, lane = tid & 63;
  int l15 = lane & 15, qd = lane >> 4;

  int ra0 = tid >> 2,          qa0 = (tid & 3) ^ ((ra0 >> 1) & 3);
  int ra1 = (tid + 256) >> 2,  qa1 = (tid & 3) ^ ((ra1 >> 1) & 3);
  const u16* gA0 = A + (long)(m0 + ra0) * K + qa0 * 8;
  const u16* gA1 = A + (long)(m0 + ra1) * K + qa1 * 8;
  const u16* gB0 = B + (long)(n0 + ra0) * K + qa0 * 8;
  const u16* gB1 = B + (long)(n0 + ra1) * K + qa1 * 8;

  int wm = wave & 1, wn = wave >> 1;
  int aoff[4], boff[4];
#pragma unroll
  for (int i = 0; i < 4; i++) {
    int r = wm * 64 + i * 16 + l15;
    aoff[i] = r * 32 + ((qd ^ ((r >> 1) & 3)) * 8);
    int rb = wn * 64 + i * 16 + l15;
    boff[i] = rb * 32 + ((qd ^ ((rb >> 1) & 3)) * 8);
  }

  f32x4 zero = {0.f, 0.f, 0.f, 0.f};
  f32x4 acc[4][4];
#pragma unroll
  for (int i = 0; i < 4; i++)
#pragma unroll
    for (int j = 0; j < 4; j++) acc[i][j] = zero;

#define STAGE2(buf, kt) { \
    u16* dA = smem + (buf) * 8192 + wave * 512; \
    u16* dB = smem + (buf) * 8192 + 4096 + wave * 512; \
    GLOAD16(gA0 + (kt) * 32, dA); GLOAD16(gA1 + (kt) * 32, dA + 2048); \
    GLOAD16(gB0 + (kt) * 32, dB); GLOAD16(gB1 + (kt) * 32, dB + 2048); }

  STAGE2(0, 0); STAGE2(1, 1);
  asm volatile("s_waitcnt vmcnt(4)" ::: "memory");
  __builtin_amdgcn_s_barrier();

#pragma unroll
  for (int tt = 0; tt < 16; tt++) {
    if (tt < 14) STAGE2((tt + 2) % 3, tt + 2);
    const u16* Ac = smem + (tt % 3) * 8192;
    const u16* Bc = smem + (tt % 3) * 8192 + 4096;
    bf16x8 af[4], bf[4];
#pragma unroll
    for (int q = 0; q < 4; q++) {
      af[q] = *(const bf16x8*)(Ac + aoff[q]);
      bf[q] = *(const bf16x8*)(Bc + boff[q]);
    }
#pragma unroll
    for (int i = 0; i < 4; i++)
#pragma unroll
      for (int j = 0; j < 4; j++)
        acc[i][j] = __builtin_amdgcn_mfma_f32_16x16x32_bf16(af[i], bf[j], acc[i][j], 0, 0, 0);
    if (tt < 14)       { asm volatile("s_waitcnt vmcnt(4) lgkmcnt(0)" ::: "memory"); __builtin_amdgcn_s_barrier(); }
    else if (tt == 14) { asm volatile("s_waitcnt vmcnt(0) lgkmcnt(0)" ::: "memory"); __builtin_amdgcn_s_barrier(); }
  }
  asm volatile("s_waitcnt vmcnt(0) lgkmcnt(0)" ::: "memory");
  __builtin_amdgcn_s_barrier();
#undef STAGE2

#pragma unroll
  for (int half = 0; half < 2; half++) {
    __syncthreads();
    if (wm == half) {
#pragma unroll
      for (int i = 0; i < 4; i++)
#pragma unroll
        for (int r = 0; r < 4; r++) {
          int rrl = i * 16 + qd * 4 + r;
          float bv = bias[m0 + half * 64 + rrl];
#pragma unroll
          for (int j = 0; j < 4; j++)
            Cf[rrl * 133 + wn * 64 + j * 16 + l15] = acc[i][j][r] + bv;
        }
    }
    __syncthreads();
#pragma unroll
    for (int z = 0; z < 2; z++) {
      int rrl = z * 32 + (tid >> 3);
      int seg = tid & 7;
      float* dp = C + (long)(m0 + half * 64 + rrl) * ldc + n0;
      const float* src = Cf + rrl * 133;
#pragma unroll
      for (int p = 0; p < 4; p++)
        *(float4*)(dp + p * 32 + seg * 4) = *(const float4*)(src + p * 32 + seg * 4);
    }
  }
}

// ------------------------------------------------- launch
extern "C" void kernel_launch(void* const* d_in, const int* in_sizes, int n_in,
                              void* d_out, int out_size, void* d_ws, size_t ws_size,
                              hipStream_t stream) {
  const float* x    = (const float*)d_in[0];
  const float* lnw  = (const float*)d_in[1];
  const float* lnb  = (const float*)d_in[2];
  const float* wqkv = (const float*)d_in[3];
  const float* wout = (const float*)d_in[4];
  const float* bout = (const float*)d_in[5];
  float* out = (float*)d_out;
  char* ws = (char*)d_ws;

  u16*  h     = (u16*)(ws + 0L);              // 32 MB (b,n,d) bf16
  u16*  qexp  = (u16*)(ws + 33554432L);       // 32 MB (b,n,512) bf16
  u16*  expkT = (u16*)(ws + 67108864L);       // 32 MB (b,512,n) bf16
  u16*  vT    = (u16*)(ws + 100663296L);      // 32 MB (b,512,n) bf16
  u16*  wqkvT = (u16*)(ws + 134217728L);      // 1.5 MB
  u16*  Mt    = (u16*)(ws + 134217728L);      // 2 MB, reuses wqkvT region (after gemm1)
  float* S    = (float*)(ws + 136314880L);    // 8 KB
  float* ctx  = (float*)(ws + 0L);            // 512 KB, aliases h (dead after gemm1)
  float* Z    = (float*)d_out;                // 1 MB, holds 1/Z (written by gemm1), dead before gemm_tn_f

  transpose_f2b<<<dim3(24, 8), 256, 0, stream>>>(wqkv, wqkvT, 512, 1536, S);

  ln_kernel<<<dim3(256, 4), 256, 0, stream>>>(x, lnw, lnb, h);

  gemm1<<<dim3(12, 256), 256, 0, stream>>>(h, wqkvT, qexp, expkT, vT, S, Z);

  hipMemsetAsync(ctx, 0, 4 * 8 * 64 * 64 * 4, stream);

  ctx_kernel<<<dim3(16, 8, 4), 256, 0, stream>>>(expkT, vT, Z, ctx);

  mprime<<<dim3(8, 8, 4), 256, 0, stream>>>(ctx, wout, S, Mt);

  gemm_tn_f<<<dim3(4, 64, 4), 256, 0, stream>>>(Mt, qexp, out, bout, 512, 8192,
                                                262144L, (long)8192 * 512, (long)512 * 8192);
}